// Round 9
// baseline (214.633 us; speedup 1.0000x reference)
//
#include <hip/hip_runtime.h>
#include <math.h>

// ---------------- model dims ----------------
#define NIMG   2048
#define EMB    128
#define NB     1024
#define WCTX   6
#define CPW    5
#define NEG    5
#define MNOISE 512
#define NWRD   11264
#define NPOSW  6144
#define TT     5

typedef __bf16 bf16x8 __attribute__((ext_vector_type(8)));
typedef float  f32x4  __attribute__((ext_vector_type(4)));
typedef float  f32x16 __attribute__((ext_vector_type(16)));

__device__ __forceinline__ float sigf(float x){ return __fdividef(1.0f, 1.0f+__expf(-x)); }
__device__ __forceinline__ float ftanh(float x){
  float xc = fminf(15.f, fmaxf(-15.f, x));
  float t = __expf(2.f*xc);
  return __fdividef(t - 1.f, t + 1.f);
}
__device__ __forceinline__ float splus(float z){
  return (z > 0.0f) ? z + log1pf(expf(-z)) : log1pf(expf(z));
}
__device__ __forceinline__ float clip10(float x){ return fminf(10.0f, fmaxf(-10.0f, x)); }
__device__ __forceinline__ float wsum64(float v){
  #pragma unroll
  for (int m = 1; m < 64; m <<= 1) v += __shfl_xor(v, m);
  return v;
}
__device__ __forceinline__ unsigned short f2b(float x){
  union { float f; unsigned u; } v; v.f = x;
  unsigned r = v.u + 0x7fff + ((v.u >> 16) & 1);
  return (unsigned short)(r >> 16);
}
__device__ __forceinline__ float b2f(unsigned short h){
  union { unsigned u; float f; } v; v.u = ((unsigned)h) << 16; return v.f;
}
__device__ __forceinline__ bf16x8 as_bf(uint4 u){
  union { uint4 q; bf16x8 v; } c; c.q = u; return c.v;
}

// ---------------- mega prep ----------------
__global__ void k_prep(
  const float* __restrict__ wi_f, const float* __restrict__ wh_f,
  const float* __restrict__ wi_b, const float* __restrict__ wh_b,
  const float* __restrict__ a1w, const float* __restrict__ a3w,
  const float* __restrict__ c2w,
  const float* __restrict__ bi_f, const float* __restrict__ bh_f,
  const float* __restrict__ bi_b, const float* __restrict__ bh_b,
  const float* __restrict__ a2b, const float* __restrict__ v_emb,
  const int* __restrict__ pos_v, const int* __restrict__ w2c,
  unsigned short* __restrict__ wpf, unsigned short* __restrict__ wpb,
  unsigned short* __restrict__ a1p, unsigned short* __restrict__ a3p,
  unsigned short* __restrict__ c2p,
  float* __restrict__ bsf, float* __restrict__ bsb, float* __restrict__ sbuf,
  float* __restrict__ vbuf, float* __restrict__ vnorm,
  int* __restrict__ chars, float* __restrict__ st, float* __restrict__ scacc,
  float* __restrict__ fcout, float* __restrict__ norms2, int nvocab)
{
  int id = blockIdx.x*256 + threadIdx.x;
  if (id < 262144){
    int dir = id >> 17;
    int lid = id & 131071;
    const float* wi = dir ? wi_b : wi_f;
    const float* wh = dir ? wh_b : wh_f;
    unsigned short* out = dir ? wpb : wpf;
    int j = lid&7, l = (lid>>3)&63, p = (lid>>9)&31, s = lid>>14;
    int wn = p>>3, nf = p&7;
    int gate = nf&3, jb = wn*2 + (nf>>2);
    int n = gate*128 + jb*16 + (l&15);
    int k = s*32 + ((l>>4)<<3) + j;
    float v = (k < 128) ? wi[n*128+k] : wh[n*128 + (k-128)];
    out[lid] = f2b(v);
  } else if (id < 327680){
    int lid = id - 262144;
    int seg = lid >> 15;
    int pid = lid & 32767;
    const float* W = seg ? a3w : a1w;
    unsigned short* out = seg ? a3p : a1p;
    int j = pid&7, l = (pid>>3)&63, rest = pid>>9;
    int p = rest & 7, s = rest >> 3;
    int n = p*16 + (l&15);
    int k = s*32 + ((l>>4)<<3) + j;
    out[pid] = f2b(W[n*256 + k]);
  } else if (id < 336896){
    int pid = id - 327680;
    int j = pid & 7, l = (pid >> 3) & 63, p = (pid >> 9) & 1, t9 = pid >> 10;
    int oc = p*16 + (l & 15), ic = ((l >> 4) << 3) + j;
    c2p[pid] = f2b(c2w[oc*288 + ic*9 + t9]);
  } else if (id < 337408){
    int i = id - 336896;
    bsf[i] = bi_f[i] + bh_f[i];
    bsb[i] = bi_b[i] + bh_b[i];
  } else if (id < 393728){
    int i = id - 337408;
    sbuf[i] = a2b[0];
  } else if (id < 459264){
    int b = (id - 393728) >> 6;
    int l = id & 63;
    float s0 = 0.f, s1 = 0.f;
    for (int w = 0; w < WCTX; w++){
      int vid = pos_v[b*WCTX + w];
      s0 += v_emb[(size_t)vid*128 + l];
      s1 += v_emb[(size_t)vid*128 + 64 + l];
    }
    s0 *= (1.f/6.f); s1 *= (1.f/6.f);
    vbuf[b*128 + l] = s0; vbuf[b*128 + 64 + l] = s1;
    float nn = wsum64(s0*s0 + s1*s1);
    if (l == 0) vnorm[b] = sqrtf(nn);
  } else if (id < 489984){
    int i = id - 459264;
    int wi_ = i / CPW, t = i - wi_*CPW;
    chars[i] = w2c[pos_v[wi_]*CPW + t];
  } else if (id < 491008){
    st[id - 489984] = 0.f;
  } else if (id < 494464){
    scacc[id - 491008] = 0.f;
  } else if (id < 756608){
    fcout[id - 494464] = 0.f;
  } else if (id < 1556608){
    int lid = id - 756608;
    int row = lid >> 4, s = id & 15;
    if (row < nvocab){
      const float4* vp = (const float4*)(v_emb + (size_t)row*128 + s*8);
      float4 x0 = vp[0], x1 = vp[1];
      float q = x0.x*x0.x + x0.y*x0.y + x0.z*x0.z + x0.w*x0.w
              + x1.x*x1.x + x1.y*x1.y + x1.z*x1.z + x1.w*x1.w;
      q += __shfl_xor(q, 1); q += __shfl_xor(q, 2);
      q += __shfl_xor(q, 4); q += __shfl_xor(q, 8);
      if (s == 0) norms2[row] = q;
    }
  }
}

// ---------------- fused cosine sims + top-5 + negative char gather ----------------
// One block per batch row: 512 cosines -> LDS (identical arithmetic/lane map to
// the old k_cos2), then wave 0 runs the old k_topk verbatim from LDS. Removes
// one launch + 4MB cosb round-trip. Runs right after k_prep (no CNN dep) so
// v_emb is L2/L3-warm from prep's norms pass.
__global__ __launch_bounds__(256) void k_cos2topk(const int* __restrict__ noise,
    const float* __restrict__ v_emb, const float* __restrict__ vbuf,
    const float* __restrict__ vnorm, const float* __restrict__ norms2,
    const int* __restrict__ w2c, int* __restrict__ neg_ids, int* __restrict__ chars)
{
  __shared__ float cs[MNOISE];
  __shared__ int nid_s[NEG];
  int b = blockIdx.x, tid = threadIdx.x;
  int s = tid & 15;
  int rsub = (tid >> 4) & 3;
  int wid = tid >> 6;
  const float4* ep = (const float4*)(vbuf + b*128 + s*8);
  float4 e0 = ep[0], e1 = ep[1];
  float nb = vnorm[b];
  int base = b*MNOISE;
  #pragma unroll
  for (int y = 0; y < 4; y++){
    int mbase = y*128 + wid*4 + rsub;
    #pragma unroll 4
    for (int iter = 0; iter < 8; iter++){
      int m = mbase + iter*16;
      int id = noise[base + m];
      const float4* vp = (const float4*)(v_emb + (size_t)id*128 + s*8);
      float4 x0 = vp[0], x1 = vp[1];
      float d = e0.x*x0.x + e0.y*x0.y + e0.z*x0.z + e0.w*x0.w
              + e1.x*x1.x + e1.y*x1.y + e1.z*x1.z + e1.w*x1.w;
      d += __shfl_xor(d, 1); d += __shfl_xor(d, 2);
      d += __shfl_xor(d, 4); d += __shfl_xor(d, 8);
      if (s == 0){
        float q = norms2[id];
        cs[m] = d / fmaxf(nb*sqrtf(q), 1e-8f);
      }
    }
  }
  __syncthreads();
  if (tid < 64){
    int l = tid;
    float v[8];
    #pragma unroll
    for (int q = 0; q < 8; q++) v[q] = cs[l + 64*q];
    for (int r = 0; r < NEG; r++){
      float bv = -1e30f; int bidx = 1<<30;
      #pragma unroll
      for (int q = 0; q < 8; q++){
        int idx = l + 64*q;
        if (v[q] > bv || (v[q] == bv && idx < bidx)){ bv = v[q]; bidx = idx; }
      }
      #pragma unroll
      for (int m = 1; m < 64; m <<= 1){
        float ov = __shfl_xor(bv, m);
        int   oi = __shfl_xor(bidx, m);
        if (ov > bv || (ov == bv && oi < bidx)){ bv = ov; bidx = oi; }
      }
      if (l == 0){
        int nid = noise[base + bidx];
        neg_ids[b*NEG + r] = nid;
        nid_s[r] = nid;
      }
      int qsel = bidx >> 6;
      #pragma unroll
      for (int q = 0; q < 8; q++)
        if (q == qsel && (bidx & 63) == l) v[q] = -1e30f;
    }
  }
  __syncthreads();
  if (tid < NEG*CPW){
    int k = tid / CPW, t = tid - k*CPW;
    chars[(NPOSW + b*NEG + k)*CPW + t] = w2c[nid_s[k]*CPW + t];
  }
}

// ---------------- conv1 stats: 4 images per block ----------------
__global__ __launch_bounds__(256) void k_stats1(
    const float* __restrict__ img, float* __restrict__ SC)
{
  __shared__ float im[1444];
  __shared__ float SCw[4][54];
  int tid = threadIdx.x;
  float S[9], C[45];
  #pragma unroll
  for (int a = 0; a < 9; a++) S[a] = 0.f;
  #pragma unroll
  for (int a = 0; a < 45; a++) C[a] = 0.f;
  for (int ii = 0; ii < 4; ii++){
    int n = blockIdx.x*4 + ii;
    const float* ip = img + (size_t)n*1444;
    __syncthreads();
    for (int i = tid; i < 1444; i += 256) im[i] = ip[i];
    __syncthreads();
    for (int p = tid; p < 1296; p += 256){
      int oh = p/36, ow = p - oh*36;
      float P[9];
      #pragma unroll
      for (int i = 0; i < 3; i++)
        #pragma unroll
        for (int j = 0; j < 3; j++)
          P[i*3+j] = im[(oh+i)*38 + ow + j];
      int idx = 0;
      #pragma unroll
      for (int a = 0; a < 9; a++){
        S[a] += P[a];
        #pragma unroll
        for (int b = a; b < 9; b++){ C[idx] += P[a]*P[b]; idx++; }
      }
    }
  }
  #pragma unroll
  for (int a = 0; a < 9; a++) S[a] = wsum64(S[a]);
  #pragma unroll
  for (int a = 0; a < 45; a++) C[a] = wsum64(C[a]);
  if ((tid & 63) == 0){
    int w = tid >> 6;
    #pragma unroll
    for (int a = 0; a < 9; a++) SCw[w][a] = S[a];
    #pragma unroll
    for (int a = 0; a < 45; a++) SCw[w][9+a] = C[a];
  }
  __syncthreads();
  if (tid < 54){
    float v = SCw[0][tid] + SCw[1][tid] + SCw[2][tid] + SCw[3][tid];
    atomicAdd(&SC[tid*64 + (blockIdx.x & 63)], v);
  }
}

// ---------------- BN1 finalize + fold into conv1 weights/bias ----------------
// also zeroes the stp partial buffer for k_conv12 (runs right before it)
__global__ void k_fold1(const float* __restrict__ SC, const float* __restrict__ c1w,
                        const float* __restrict__ c1b, const float* __restrict__ g1,
                        const float* __restrict__ b1,
                        unsigned short* __restrict__ c1p, float* __restrict__ bias1c,
                        float* __restrict__ stp)
{
  __shared__ float S[9], C[45];
  __shared__ float scs[32];
  int tid = threadIdx.x;   // 64
  #pragma unroll
  for (int k = 0; k < 64; k++) stp[k*64 + tid] = 0.f;
  if (tid < 54){
    float acc = 0.f;
    for (int s = 0; s < 64; s++) acc += SC[tid*64 + s];
    if (tid < 9) S[tid] = acc; else C[tid-9] = acc;
  }
  __syncthreads();
  if (tid < 32){
    const float invN = 1.0f/2654208.0f;
    float w[9];
    #pragma unroll
    for (int a = 0; a < 9; a++) w[a] = c1w[tid*9+a];
    float b = c1b[tid];
    float sum = 0.f;
    #pragma unroll
    for (int a = 0; a < 9; a++) sum += w[a]*S[a];
    float sq = 0.f; int idx = 0;
    #pragma unroll
    for (int a = 0; a < 9; a++)
      #pragma unroll
      for (int bb_ = a; bb_ < 9; bb_++){
        float f = (bb_ == a) ? w[a]*w[a] : 2.f*w[a]*w[bb_];
        sq += f*C[idx]; idx++;
      }
    float Epre = sum*invN;
    float var = sq*invN - Epre*Epre;
    float m = Epre + b;
    float sc = g1[tid]*rsqrtf(var + 1e-5f);
    scs[tid] = sc;
    bias1c[tid] = sc*b + (b1[tid] - m*sc);
  }
  __syncthreads();
  {
    int l = tid;
    int ch = l & 31;
    float sc = scs[ch];
    #pragma unroll
    for (int j = 0; j < 8; j++){
      int k = ((l >> 5) << 3) + j;
      int kh = k >> 2, kw = k & 3;
      float v = (kh < 3 && kw < 3) ? c1w[ch*9 + kh*3 + kw]*sc : 0.f;
      c1p[l*8+j] = f2b(v);
    }
  }
}

// ---------------- fused conv1+conv2 ----------------
// R3 structure + spread BN2-stat atomics. NEW: bfr[9] c2pack loads hoisted to
// kernel start — latency hides under img staging + conv1 (was serialized
// load->MFMA after the mid barrier); still one temporal burst so c2pack stays
// L2-resident (R4 lesson). Costs ~+36 VGPR (live across conv1), which stays
// above the measured ~2.7 blocks/CU residency.
__global__ __launch_bounds__(512) void k_conv12(
    const float* __restrict__ img, const unsigned short* __restrict__ c1p,
    const float* __restrict__ bias1c, const unsigned short* __restrict__ c2pack,
    const float* __restrict__ c2b,
    unsigned short* __restrict__ flat2, float* __restrict__ stp)
{
  __shared__ __align__(16) unsigned short Ai[1520];
  __shared__ __align__(16) unsigned short Bi[1520];
  __shared__ __align__(16) unsigned short Pt[324*32];
  __shared__ float lsum[32], lsq[32];
  int n = blockIdx.x, tid = threadIdx.x;
  int l = tid & 63, w = tid >> 6;
  int wN = w & 1;
  bf16x8 bfr[9];
  #pragma unroll
  for (int t9 = 0; t9 < 9; t9++)
    bfr[t9] = as_bf(*(const uint4*)(c2pack + ((size_t)(t9*2 + wN)*64 + l)*8));
  if (tid < 190){
    int r = tid/5, c = tid - r*5;
    if (c < 2) Ai[r*40 + 38 + c] = 0;
    else       Bi[r*40 + 37 + (c-2)] = 0;
  }
  if (tid >= 192 && tid < 224){ lsum[tid-192] = 0.f; }
  if (tid >= 224 && tid < 256){ lsq[tid-224] = 0.f; }
  const float4* ip4 = (const float4*)(img + (size_t)n*1444);
  for (int i = tid; i < 361; i += 512){
    float4 v = ip4[i];
    int flat = i*4;
    const float* pv = (const float*)&v;
    #pragma unroll
    for (int e = 0; e < 4; e++){
      int f = flat + e;
      int r = f / 38, c = f - r*38;
      unsigned short h = f2b(pv[e]);
      Ai[r*40 + c] = h;
      if (c) Bi[r*40 + c - 1] = h;
    }
  }
  __syncthreads();
  {
    int hi = l >> 5;
    int ch = l & 31;
    int r31 = l & 31;
    int member = r31 & 3;
    const unsigned short* P = (member & 1) ? Bi : Ai;
    int rowoff = (member >> 1) * 40;
    bf16x8 bw = as_bf(*(const uint4*)(c1p + (size_t)l*8));
    float bias = bias1c[ch];
    int inoff = (ch & 7)*2;
    int chgrp = ch >> 3;
    #pragma unroll 2
    for (int g = w; g < 41; g += 8){
      int ql = g*8 + (r31 >> 2);
      if (ql > 323) ql = 323;
      int ph = ql/18, pw = ql - ph*18;
      int off = (2*ph)*40 + rowoff + 2*pw;
      uint4 a = (uint4){0u,0u,0u,0u};
      if (hi == 0){
        const unsigned* p0 = (const unsigned*)(P + off);
        const unsigned* p1 = (const unsigned*)(P + off + 40);
        a.x = p0[0]; a.y = p0[1]; a.z = p1[0]; a.w = p1[1];
      } else {
        const unsigned* p2 = (const unsigned*)(P + off + 80);
        a.x = p2[0]; a.y = p2[1];
      }
      f32x16 acc = __builtin_amdgcn_mfma_f32_32x32x16_bf16(
          as_bf(a), bw,
          (f32x16){0.f,0.f,0.f,0.f,0.f,0.f,0.f,0.f,0.f,0.f,0.f,0.f,0.f,0.f,0.f,0.f},
          0, 0, 0);
      #pragma unroll
      for (int rg = 0; rg < 4; rg++){
        int qo = g*8 + rg*2 + hi;
        if (qo < 324){
          float v0 = acc[rg*4+0]+bias, v1 = acc[rg*4+1]+bias;
          float v2 = acc[rg*4+2]+bias, v3 = acc[rg*4+3]+bias;
          float mx = fmaxf(fmaxf(v0,v1), fmaxf(v2,v3));
          *(unsigned short*)((char*)Pt + qo*64 + (((chgrp ^ (qo & 3)) << 4) + inoff)) = f2b(mx);
        }
      }
    }
  }
  __syncthreads();
  int wM = w >> 1;
  f32x4 acc[4];
  #pragma unroll
  for (int mf = 0; mf < 4; mf++) acc[mf] = (f32x4){0.f,0.f,0.f,0.f};
  #pragma unroll
  for (int t9 = 0; t9 < 9; t9++){
    int kh = t9/3, kw = t9 - (t9/3)*3;
    #pragma unroll
    for (int mf = 0; mf < 4; mf++){
      int pos = wM*64 + mf*16 + (l & 15);
      int oh = pos >> 4, ow = pos & 15;
      int q = (oh + kh)*18 + (ow + kw);
      int slot = ((l >> 4) ^ q) & 3;
      bf16x8 a = as_bf(*(const uint4*)((const char*)Pt + q*64 + slot*16));
      acc[mf] = __builtin_amdgcn_mfma_f32_16x16x32_bf16(a, bfr[t9], acc[mf], 0, 0, 0);
    }
  }
  int oc = wN*16 + (l & 15);
  int qq = l >> 4;
  float bb = c2b[oc];
  float vm[4][4];
  float s = 0.f, sq = 0.f;
  #pragma unroll
  for (int mf = 0; mf < 4; mf++)
    #pragma unroll
    for (int reg = 0; reg < 4; reg++){
      float v = acc[mf][reg] + bb;
      vm[mf][reg] = v;
      s += v; sq += v*v;
    }
  s += __shfl_xor(s,16); sq += __shfl_xor(sq,16);
  s += __shfl_xor(s,32); sq += __shfl_xor(sq,32);
  if (qq == 0){ atomicAdd(&lsum[oc], s); atomicAdd(&lsq[oc], sq); }
  unsigned short* fp = flat2 + (size_t)n*2048 + oc*64;
  #pragma unroll
  for (int mp = 0; mp < 2; mp++){
    int ph = wM*2 + mp;
    float p0 = fmaxf(fmaxf(vm[2*mp][0], vm[2*mp][1]), fmaxf(vm[2*mp+1][0], vm[2*mp+1][1]));
    float p1 = fmaxf(fmaxf(vm[2*mp][2], vm[2*mp][3]), fmaxf(vm[2*mp+1][2], vm[2*mp+1][3]));
    unsigned pk = ((unsigned)f2b(p1) << 16) | (unsigned)f2b(p0);
    *(unsigned*)(fp + ph*8 + qq*2) = pk;
  }
  __syncthreads();
  if (tid < 32){
    int slot = (blockIdx.x & 63)*64;
    atomicAdd(&stp[slot + tid], lsum[tid]);
    atomicAdd(&stp[slot + 32 + tid], lsq[tid]);
  }
}

// ---------------- fc pack with BN2 scale folded (+ inline 64-slot fold) ----------------
// Each block cooperatively folds the 64x64 stp partials into LDS (same
// ascending-s order as the old k_fold2 => bit-exact), then scales. Removes
// the separate 1-block k_fold2 launch.
__global__ __launch_bounds__(256) void k_fcscale(const float* __restrict__ fcw,
                          const float* __restrict__ stp,
                          const float* __restrict__ g2, unsigned short* __restrict__ fcp)
{
  __shared__ float fs[64];
  int tid = threadIdx.x;
  if (tid < 64){
    float acc = 0.f;
    #pragma unroll 8
    for (int s = 0; s < 64; s++) acc += stp[s*64 + tid];
    fs[tid] = acc;
  }
  __syncthreads();
  int id = blockIdx.x*256 + tid;
  if (id >= 262144) return;
  int j = id&7, lq = (id>>3)&63, rest = id>>9;
  int p = rest & 7, sg = rest >> 3;
  int n = p*16 + (lq&15);
  int k = sg*32 + ((lq>>4)<<3) + j;
  int c = k >> 6;
  float m = fs[c]*(1.f/524288.f);
  float var = fs[32+c]*(1.f/524288.f) - m*m;
  float sc = g2[c]*rsqrtf(var + 1e-5f);
  fcp[id] = f2b(fcw[(size_t)n*2048 + k] * sc);
}

// ---------------- generic MFMA GEMM, N=128 ----------------
__global__ __launch_bounds__(512) void k_gemm_mfma(
    const unsigned short* __restrict__ A0, const unsigned short* __restrict__ A1,
    const unsigned short* __restrict__ wpack, const float* __restrict__ bias,
    float* __restrict__ out, const float* __restrict__ a2w, float* __restrict__ sbuf,
    int M, int K, int fuse)
{
  __shared__ unsigned short At[64*256];
  __shared__ float wt[64][5];
  int tid = threadIdx.x;
  int l = tid & 63, wid = tid >> 6;
  int row0 = blockIdx.x * 64;
  int wm = wid >> 2, wn = wid & 3;
  int kspan = K / gridDim.y;
  int kbeg = blockIdx.y * kspan;
  f32x4 acc[2][2];
  #pragma unroll
  for (int a = 0; a < 2; a++)
    #pragma unroll
    for (int b = 0; b < 2; b++) acc[a][b] = (f32x4){0.f,0.f,0.f,0.f};

  if (fuse == 3){
    if (tid < 64){
      int gr = row0 + tid;
      float sv[TT];
      float mx = -1e30f;
      #pragma unroll
      for (int t = 0; t < TT; t++){ sv[t] = sbuf[t*NWRD + gr]; mx = fmaxf(mx, sv[t]); }
      float sum = 0.f;
      #pragma unroll
      for (int t = 0; t < TT; t++){ sv[t] = __expf(sv[t] - mx); sum += sv[t]; }
      float inv = __fdividef(1.f, sum);
      #pragma unroll
      for (int t = 0; t < TT; t++) wt[tid][t] = sv[t]*inv;
    }
    __syncthreads();
  }

  for (int kc = kbeg; kc < kbeg + kspan; kc += 256){
    #pragma unroll
    for (int it = 0; it < 4; it++){
      int ci = tid + 512*it;
      int r = ci >> 5, c = ci & 31;
      int gr = row0 + r; int k = kc + c*8;
      uint4 v;
      if (fuse == 3){
        int col = (k < 128) ? k : (k - 128);
        const unsigned short* sp = (k < 128) ? A0 : A1;
        float a8[8];
        #pragma unroll
        for (int e = 0; e < 8; e++) a8[e] = 0.f;
        #pragma unroll
        for (int t = 0; t < TT; t++){
          uint4 hv = *(const uint4*)(sp + ((size_t)t*NWRD + gr)*128 + col);
          const unsigned short* ph = (const unsigned short*)&hv;
          float wgt = wt[r][t];
          #pragma unroll
          for (int e = 0; e < 8; e++) a8[e] += wgt * b2f(ph[e]);
        }
        unsigned short o[8];
        #pragma unroll
        for (int e = 0; e < 8; e++) o[e] = f2b(a8[e]);
        v = *(uint4*)o;
      } else {
        const unsigned short* src;
        if (A1) src = (k < 128) ? (A0 + (size_t)gr*128 + k) : (A1 + (size_t)gr*128 + (k-128));
        else    src = A0 + (size_t)gr*K + k;
        v = *(const uint4*)src;
      }
      *(uint4*)((char*)At + r*512 + ((c*16) ^ ((r & 7) << 4))) = v;
    }
    __syncthreads();
    #pragma unroll
    for (int s8 = 0; s8 < 8; s8++){
      int s = (kc >> 5) + s8;
      bf16x8 af[2];
      #pragma unroll
      for (int mf = 0; mf < 2; mf++){
        int r = wm*32 + mf*16 + (l & 15);
        int cb = (s8*4 + (l >> 4)) ^ (r & 7);
        af[mf] = as_bf(*(const uint4*)((const char*)At + r*512 + cb*16));
      }
      #pragma unroll
      for (int nf = 0; nf < 2; nf++){
        bf16x8 bf_ = as_bf(*(const uint4*)(wpack + ((size_t)(s*8 + wn*2 + nf)*64 + l)*8));
        acc[0][nf] = __builtin_amdgcn_mfma_f32_16x16x32_bf16(af[0], bf_, acc[0][nf], 0,0,0);
        acc[1][nf] = __builtin_amdgcn_mfma_f32_16x16x32_bf16(af[1], bf_, acc[1][nf], 0,0,0);
      }
    }
    __syncthreads();
  }
  if (fuse == 0 || fuse == 3){
    #pragma unroll
    for (int mf = 0; mf < 2; mf++)
      #pragma unroll
      for (int nf = 0; nf < 2; nf++)
        #pragma unroll
        for (int reg = 0; reg < 4; reg++){
          int row = row0 + wm*32 + mf*16 + ((l >> 4) << 2) + reg;
          int col = wn*32 + nf*16 + (l & 15);
          out[(size_t)row*128 + col] = acc[mf][nf][reg] + bias[col];
        }
  } else if (fuse == 2){
    #pragma unroll
    for (int mf = 0; mf < 2; mf++)
      #pragma unroll
      for (int nf = 0; nf < 2; nf++)
        #pragma unroll
        for (int reg = 0; reg < 4; reg++){
          int row = row0 + wm*32 + mf*16 + ((l >> 4) << 2) + reg;
          int col = wn*32 + nf*16 + (l & 15);
          atomicAdd(&out[(size_t)row*128 + col], acc[mf][nf][reg]);
        }
  } else {
    float part[2][4];
    #pragma unroll
    for (int mf = 0; mf < 2; mf++)
      #pragma unroll
      for (int reg = 0; reg < 4; reg++){
        float p = 0.f;
        #pragma unroll
        for (int nf = 0; nf < 2; nf++){
          int col = wn*32 + nf*16 + (l & 15);
          p += ftanh(acc[mf][nf][reg] + bias[col]) * a2w[col];
        }
        part[mf][reg] = p;
      }
    #pragma unroll
    for (int msk = 1; msk < 16; msk <<= 1)
      #pragma unroll
      for (int mf = 0; mf < 2; mf++)
        #pragma unroll
        for (int reg = 0; reg < 4; reg++)
          part[mf][reg] += __shfl_xor(part[mf][reg], msk);
    if ((l & 15) == 0){
      #pragma unroll
      for (int mf = 0; mf < 2; mf++)
        #pragma unroll
        for (int reg = 0; reg < 4; reg++)
          atomicAdd(&sbuf[row0 + wm*32 + mf*16 + ((l >> 4) << 2) + reg], part[mf][reg]);
    }
  }
}

// ---------------- BN1d fused ----------------
__global__ __launch_bounds__(256) void k_bn1d_fused(const float* __restrict__ fc,
    const float* __restrict__ g3, const float* __restrict__ b3,
    unsigned short* __restrict__ img_emb)
{
  int j = blockIdx.x, tid = threadIdx.x;
  float vr[8];
  float s = 0.f, q = 0.f;
  #pragma unroll
  for (int u = 0; u < 8; u++){
    float v = fc[(u*256 + tid)*128 + j];
    vr[u] = v; s += v; q += v*v;
  }
  s = wsum64(s); q = wsum64(q);
  __shared__ float rs[4], rq[4];
  if ((tid & 63) == 0){ rs[tid>>6] = s; rq[tid>>6] = q; }
  __syncthreads();
  float S = rs[0]+rs[1]+rs[2]+rs[3];
  float Q = rq[0]+rq[1]+rq[2]+rq[3];
  float m = S*(1.f/2048.f);
  float var = Q*(1.f/2048.f) - m*m;
  float sc = g3[j]*rsqrtf(var + 1e-5f);
  float sh = b3[j] - m*sc;
  #pragma unroll
  for (int u = 0; u < 8; u++)
    img_emb[(u*256 + tid)*128 + j] = f2b(fmaxf(0.f, vr[u]*sc + sh));
}

// ---------------- LSTM x-projection -> bf16 packed gates ----------------
__global__ __launch_bounds__(256) void k_xproj(
    const unsigned short* __restrict__ xemb,
    const unsigned short* __restrict__ wpf, const unsigned short* __restrict__ wpb,
    const float* __restrict__ bsf, const float* __restrict__ bsb,
    unsigned short* __restrict__ xgf, unsigned short* __restrict__ xgb)
{
  __shared__ unsigned short At[64*128];
  int dir = blockIdx.z;
  const unsigned short* wpack = dir ? wpb : wpf;
  const float* bsum = dir ? bsb : bsf;
  unsigned short* xg = dir ? xgb : xgf;
  int tid = threadIdx.x;
  int l = tid & 63, wid = tid >> 6;
  int row0 = blockIdx.x * 64;
  int wm = wid >> 1;
  int wn = blockIdx.y*2 + (wid & 1);
  #pragma unroll
  for (int it = 0; it < 4; it++){
    int ci = tid + 256*it;
    int r = ci >> 4, c = ci & 15;
    uint4 v = *(const uint4*)(xemb + (size_t)(row0 + r)*128 + c*8);
    *(uint4*)((char*)At + r*256 + ((c*16) ^ ((r & 7) << 4))) = v;
  }
  __syncthreads();
  f32x4 acc[2][8];
  #pragma unroll
  for (int a = 0; a < 2; a++)
    #pragma unroll
    for (int b = 0; b < 8; b++) acc[a][b] = (f32x4){0.f,0.f,0.f,0.f};
  #pragma unroll
  for (int s4 = 0; s4 < 4; s4++){
    bf16x8 af[2];
    #pragma unroll
    for (int mf = 0; mf < 2; mf++){
      int r = wm*32 + mf*16 + (l & 15);
      int cb = (s4*4 + (l >> 4)) ^ (r & 7);
      af[mf] = as_bf(*(const uint4*)((const char*)At + r*256 + cb*16));
    }
    #pragma unroll
    for (int nf = 0; nf < 8; nf++){
      bf16x8 bf_ = as_bf(*(const uint4*)(wpack + ((size_t)(s4*32 + wn*8 + nf)*64 + l)*8));
      acc[0][nf] = __builtin_amdgcn_mfma_f32_16x16x32_bf16(af[0], bf_, acc[0][nf], 0,0,0);
      acc[1][nf] = __builtin_amdgcn_mfma_f32_16x16x32_bf16(af[1], bf_, acc[1][nf], 0,0,0);
    }
  }
  #pragma unroll
  for (int mf = 0; mf < 2; mf++)
    #pragma unroll
    for (int reg = 0; reg < 4; reg++){
      int gr = row0 + wm*32 + mf*16 + ((l >> 4) << 2) + reg;
      unsigned short* xrow = xg + (size_t)gr*512;
      #pragma unroll
      for (int js = 0; js < 2; js++){
        int jl = wn*32 + js*16 + (l & 15);
        unsigned short o[4];
        o[0] = f2b(acc[mf][js*4+0][reg] + bsum[jl]);
        o[1] = f2b(acc[mf][js*4+1][reg] + bsum[128+jl]);
        o[2] = f2b(acc[mf][js*4+2][reg] + bsum[256+jl]);
        o[3] = f2b(acc[mf][js*4+3][reg] + bsum[384+jl]);
        *(uint2*)(xrow + jl*4) = *(uint2*)o;
      }
    }
}

// ---------------- fused 5-step dual-direction LSTM ----------------
// R5-proven version (46.6us), FROZEN: 1408 blocks x one 16-row tile; hh
// weights register-resident (16 frags = 64 VGPR, 8 waves/SIMD); post-barrier
// prefetch of next-step xv gathers; nontemporal hs flush; med3 clamps.
// R6/R7: widening per-block work loses (VGPR >64 halves waves/SIMD).
__global__ __launch_bounds__(512, 4) void k_lstm5(
    const int* __restrict__ chars,
    const unsigned short* __restrict__ wpf, const unsigned short* __restrict__ wpb,
    const unsigned short* __restrict__ xgf, const unsigned short* __restrict__ xgb,
    unsigned short* __restrict__ hsf, unsigned short* __restrict__ hsb)
{
  __shared__ __align__(16) unsigned short At[2][2048];   // 2 x 4KB swizzled h tiles
  __shared__ int cid_s[80];                               // 16 rows x 5 steps
  int b = blockIdx.x;
  int br = b & 7;
  int dir = br >> 2;
  int rblk = (b >> 3)*4 + (br & 3);        // 0..703 per dir
  const unsigned short* wpack = dir ? wpb : wpf;
  const unsigned short* xg = dir ? xgb : xgf;
  unsigned short* hs = dir ? hsb : hsf;
  int tid = threadIdx.x;
  int l = tid & 63, c = tid >> 6;          // c = 16-col h-slice 0..7
  int jl = c*16 + (l & 15);                // global h column
  int row0 = rblk * 16;

  if (tid < 80) cid_s[tid] = chars[row0*CPW + tid];

  bf16x8 wreg[4][4];
  #pragma unroll
  for (int s4 = 0; s4 < 4; s4++)
    #pragma unroll
    for (int g = 0; g < 4; g++)
      wreg[s4][g] = as_bf(*(const uint4*)(wpack + ((size_t)((s4+4)*32 + c*4 + g)*64 + l)*8));

  int frow = tid >> 5, fq = tid & 31;
  int fof = (((fq >> 1) ^ (frow & 7)) << 4) | ((fq & 1) << 3);

  __syncthreads();                          // cid_s ready

  int rbase = (l >> 4) << 2;
  int t0 = dir ? (TT-1) : 0;
  uint2 xv[4], xvn[4];
  #pragma unroll
  for (int reg = 0; reg < 4; reg++)
    xv[reg] = *(const uint2*)(xg + (size_t)cid_s[(rbase+reg)*CPW + t0]*512 + jl*4);

  float creg[4];
  #pragma unroll
  for (int reg = 0; reg < 4; reg++) creg[reg] = 0.f;
  int tprev = t0;

  #pragma unroll
  for (int tF = 0; tF < TT; tF++){
    int t = dir ? (TT-1-tF) : tF;
    f32x4 acc[4];
    if (tF > 0){
      __syncthreads();
      const unsigned short* buf = At[(tF-1) & 1];
      uint2 hv = *(const uint2*)((const char*)buf + tid*8);
      {
        union { uint2 v; unsigned long long q; } cv; cv.v = hv;
        __builtin_nontemporal_store(cv.q,
          (unsigned long long*)((char*)(hs + (size_t)tprev*NWRD*128 + (size_t)(row0 + frow)*128) + fof));
      }
      if (tF + 1 < TT){
        int tn = dir ? (TT-2-tF) : (tF+1);
        #pragma unroll
        for (int reg = 0; reg < 4; reg++)
          xvn[reg] = *(const uint2*)(xg + (size_t)cid_s[(rbase+reg)*CPW + tn]*512 + jl*4);
      }
      #pragma unroll
      for (int g = 0; g < 4; g++) acc[g] = (f32x4){0.f,0.f,0.f,0.f};
      #pragma unroll
      for (int s4 = 0; s4 < 4; s4++){
        int r = l & 15;
        int cb = (s4*4 + (l >> 4)) ^ (r & 7);
        bf16x8 af = as_bf(*(const uint4*)((const char*)buf + r*256 + cb*16));
        #pragma unroll
        for (int g = 0; g < 4; g++)
          acc[g] = __builtin_amdgcn_mfma_f32_16x16x32_bf16(af, wreg[s4][g], acc[g], 0,0,0);
      }
    } else {
      int tn = dir ? (TT-2) : 1;
      #pragma unroll
      for (int reg = 0; reg < 4; reg++)
        xvn[reg] = *(const uint2*)(xg + (size_t)cid_s[(rbase+reg)*CPW + tn]*512 + jl*4);
      #pragma unroll
      for (int g = 0; g < 4; g++) acc[g] = (f32x4){0.f,0.f,0.f,0.f};
    }
    unsigned short* wb = At[tF & 1];
    #pragma unroll
    for (int reg = 0; reg < 4; reg++){
      int rloc = ((l >> 4) << 2) + reg;
      const unsigned short* xs = (const unsigned short*)&xv[reg];
      float ig = acc[0][reg] + b2f(xs[0]);
      float fg = acc[1][reg] + b2f(xs[1]);
      float gg = acc[2][reg] + b2f(xs[2]);
      float og = acc[3][reg] + b2f(xs[3]);
      float co = creg[reg];
      float ei = __expf(-__builtin_amdgcn_fmed3f(ig, -30.f, 30.f));
      float eg = __expf(2.f*__builtin_amdgcn_fmed3f(gg, -15.f, 15.f));
      float sf = __fdividef(1.f, 1.f + __expf(-__builtin_amdgcn_fmed3f(fg, -30.f, 30.f)));
      float itg = __fdividef(eg - 1.f, (1.f + ei)*(eg + 1.f));
      float cn = sf*co + itg;
      float eo = __expf(-__builtin_amdgcn_fmed3f(og, -30.f, 30.f));
      float ec = __expf(2.f*__builtin_amdgcn_fmed3f(cn, -15.f, 15.f));
      float h  = __fdividef(ec - 1.f, (1.f + eo)*(ec + 1.f));
      creg[reg] = cn;
      int byteoff = rloc*256 + ((((jl >> 3) << 4) ^ ((rloc & 7) << 4)) + (jl & 7)*2);
      *(unsigned short*)((char*)wb + byteoff) = f2b(h);
    }
    tprev = t;
    #pragma unroll
    for (int reg = 0; reg < 4; reg++) xv[reg] = xvn[reg];
  }
  __syncthreads();
  const unsigned short* buf = At[(TT-1) & 1];
  uint2 hv = *(const uint2*)((const char*)buf + tid*8);
  {
    union { uint2 v; unsigned long long q; } cv; cv.v = hv;
    __builtin_nontemporal_store(cv.q,
      (unsigned long long*)((char*)(hs + (size_t)tprev*NWRD*128 + (size_t)(row0 + frow)*128) + fof));
  }
}

// ---------------- loss ----------------
__global__ __launch_bounds__(64) void k_loss(const int* __restrict__ pos_u,
    const float* __restrict__ u_emb, const float* __restrict__ vbuf,
    const float* __restrict__ echar, const int* __restrict__ neg_ids,
    const float* __restrict__ v_emb, float* __restrict__ part)
{
  int b = blockIdx.x, l = threadIdx.x;
  int pu = pos_u[b];
  float eu0 = u_emb[pu*128 + l], eu1 = u_emb[pu*128 + 64 + l];
  float c0 = 0.f, c1 = 0.f;
  for (int w = 0; w < WCTX; w++){
    int r = b*WCTX + w;
    c0 += echar[r*128 + l]; c1 += echar[r*128 + 64 + l];
  }
  c0 *= (1.f/6.f); c1 *= (1.f/6.f);
  float d1 = wsum64(eu0*c0 + eu1*c1);
  float d2 = wsum64(eu0*vbuf[b*128 + l] + eu1*vbuf[b*128 + 64 + l]);
  float tot = splus(-clip10(d1)) + splus(-clip10(d2));
  for (int k = 0; k < NEG; k++){
    int r = NPOSW + b*NEG + k;
    float dc = wsum64(eu0*echar[r*128 + l] + eu1*echar[r*128 + 64 + l]);
    int nid = neg_ids[b*NEG + k];
    float dn = wsum64(eu0*v_emb[nid*128 + l] + eu1*v_emb[nid*128 + 64 + l]);
    tot += splus(clip10(dc)) + splus(clip10(dn));
  }
  if (l == 0) part[b] = tot;
}

__global__ __launch_bounds__(256) void k_final(const float* __restrict__ part, float* __restrict__ out)
{
  int tid = threadIdx.x;
  float s = part[tid] + part[tid+256] + part[tid+512] + part[tid+768];
  s = wsum64(s);
  __shared__ float r[4];
  if ((tid & 63) == 0) r[tid>>6] = s;
  __syncthreads();
  if (tid == 0) out[0] = (r[0]+r[1]+r[2]+r[3]) * (1.0f/1024.0f);
}

// ---------------- launch ----------------
extern "C" void kernel_launch(void* const* d_in, const int* in_sizes, int n_in,
                              void* d_out, int out_size, void* d_ws, size_t ws_size,
                              hipStream_t stream)
{
  (void)n_in; (void)out_size; (void)ws_size;
  const int*   pos_u  = (const int*)  d_in[0];
  const int*   pos_v  = (const int*)  d_in[1];
  const int*   noise  = (const int*)  d_in[2];
  const int*   w2c    = (const int*)  d_in[3];
  const float* img    = (const float*)d_in[4];
  const float* u_emb  = (const float*)d_in[5];
  const float* v_emb  = (const float*)d_in[6];
  const float* c1w    = (const float*)d_in[7];
  const float* c1b    = (const float*)d_in[8];
  const float* g1     = (const float*)d_in[9];
  const float* b1     = (const float*)d_in[10];
  const float* c2w    = (const float*)d_in[11];
  const float* c2b    = (const float*)d_in[12];
  const float* g2     = (const float*)d_in[13];
  const float* b2     = (const float*)d_in[14];
  const float* fcw    = (const float*)d_in[15];
  const float* fcb    = (const float*)d_in[16];
  const float* g3     = (const float*)d_in[17];
  const float* b3     = (const float*)d_in[18];
  const float* wi_f   = (const float*)d_in[19];
  const float* wh_f   = (const float*)d_in[20];
  const float* bi_f   = (const float*)d_in[21];
  const float* bh_f   = (const float*)d_in[22];
  const float* wi_b   = (const float*)d_in[23];
  const float* wh_b   = (const float*)d_in[24];
  const float* bi_b   = (const float*)d_in[25];
  const float* bh_b   = (const float*)d_in[26];
  const float* a1w    = (const float*)d_in[27];
  const float* a1b    = (const float*)d_in[28];
  const float* a2w    = (const float*)d_in[29];
  const float* a2b    = (const float*)d_in[30];
  const float* a3w    = (const float*)d_in[31];
  const float* a3b    = (const float*)d_in[32];
  (void)fcb; (void)b2;
  int nvocab = in_sizes[6] / 128;

  char* ws = (char*)d_ws;
  typedef unsigned short u16;
  constexpr size_t OFF_ST   = 0;
  constexpr size_t OFF_WPF  = 4096;
  constexpr size_t OFF_WPB  = OFF_WPF + 262144;
  constexpr size_t OFF_A1P  = OFF_WPB + 262144;
  constexpr size_t OFF_A3P  = OFF_A1P + 65536;
  constexpr size_t OFF_FCP  = OFF_A3P + 65536;
  constexpr size_t OFF_C2P  = OFF_FCP + 524288;
  constexpr size_t OFF_C1P  = OFF_C2P + 18432;
  constexpr size_t OFF_BSF  = OFF_C1P + 2048;
  constexpr size_t OFF_BSB  = OFF_BSF + 2048;
  constexpr size_t OFF_SC   = OFF_BSB + 2048;
  constexpr size_t OFF_HSF  = OFF_SC + 14336;
  constexpr size_t OFF_HSB  = OFF_HSF + 14417920;
  constexpr size_t OFF_FL2  = OFF_HSB + 14417920;
  constexpr size_t OFF_ECH  = OFF_FL2 + 5767168;
  constexpr size_t OFF_FC   = OFF_ECH + 5767168;
  constexpr size_t OFF_IE   = OFF_FC  + 1048576;
  constexpr size_t OFF_VB   = OFF_IE  + 524288;
  constexpr size_t OFF_VN   = OFF_VB  + 524288;
  constexpr size_t OFF_COS  = OFF_VN  + 4096;
  constexpr size_t OFF_NI   = OFF_COS + 2097152;
  constexpr size_t OFF_CH   = OFF_NI  + 20480;
  constexpr size_t OFF_SB   = OFF_CH  + 225280;
  constexpr size_t OFF_PART = OFF_SB  + 225280;
  constexpr size_t OFF_NRM  = OFF_PART + 4096;
  constexpr size_t OFF_XGF  = OFF_NRM + 204800;
  constexpr size_t OFF_XGB  = OFF_XGF + 2097152;

  float* st      = (float*)(ws + OFF_ST);
  u16*   wpf     = (u16*)  (ws + OFF_WPF);
  u16*   wpb     = (u16*)  (ws + OFF_WPB);
  u16*   a1p     = (u16*)  (ws + OFF_A1P);
  u16*   a3p     = (u16*)  (ws + OFF_A3P);
  u16*   fcp     = (u16*)  (ws + OFF_FCP);
  u16*   c2p     = (u16*)  (ws + OFF_C2P);
  u16*   c1p     = (u16*)  (ws + OFF_C1P);
  float* bsf     = (float*)(ws + OFF_BSF);
  float* bsb     = (float*)(ws + OFF_BSB);
  float* scacc   = (float*)(ws + OFF_SC);
  u16*   flat2   = (u16*)  (ws + OFF_FL2);
  float* fcout   = (float*)(ws + OFF_FC);
  u16*   imgemb  = (u16*)  (ws + OFF_IE);
  float* vbuf    = (float*)(ws + OFF_VB);
  float* vnorm   = (float*)(ws + OFF_VN);
  int*   negi    = (int*)  (ws + OFF_NI);
  int*   charsb  = (int*)  (ws + OFF_CH);
  u16*   hsf     = (u16*)  (ws + OFF_HSF);
  u16*   hsb     = (u16*)  (ws + OFF_HSB);
  float* sb      = (float*)(ws + OFF_SB);
  float* echar   = (float*)(ws + OFF_ECH);
  float* part    = (float*)(ws + OFF_PART);
  float* norms2  = (float*)(ws + OFF_NRM);
  u16*   xgf     = (u16*)  (ws + OFF_XGF);
  u16*   xgb     = (u16*)  (ws + OFF_XGB);
  // BN2 stat partials: 64 slots x 64 values in the old cosb region (cosb
  // itself is gone — top-k now consumes cosines from LDS inside k_cos2topk)
  float* stp     = (float*)(ws + OFF_COS);

  // ---- prep ----
  k_prep<<<6081, 256, 0, stream>>>(wi_f, wh_f, wi_b, wh_b, a1w, a3w, c2w,
                                   bi_f, bh_f, bi_b, bh_b, a2b, v_emb, pos_v, w2c,
                                   wpf, wpb, a1p, a3p, c2p, bsf, bsb, sb,
                                   vbuf, vnorm, charsb, st, scacc, fcout, norms2, nvocab);

  // ---- mining (fp32 exact; fused cos+topk; v_emb L2/L3-warm from prep) ----
  k_cos2topk<<<NB, 256, 0, stream>>>(noise, v_emb, vbuf, vnorm, norms2, w2c, negi, charsb);

  // ---- CNN ----
  k_stats1<<<512, 256, 0, stream>>>(img, scacc);
  k_fold1<<<1, 64, 0, stream>>>(scacc, c1w, c1b, g1, b1, c1p, st+520, stp);
  k_conv12<<<NIMG, 512, 0, stream>>>(img, c1p, st+520, c2p, c2b, flat2, stp);
  k_fcscale<<<1024, 256, 0, stream>>>(fcw, stp, g2, fcp);
  k_gemm_mfma<<<dim3(32, 4), 512, 0, stream>>>(flat2, nullptr, fcp, nullptr, fcout,
                                               nullptr, nullptr, 2048, 2048, 2);
  k_bn1d_fused<<<128, 256, 0, stream>>>(fcout, g3, b3, imgemb);
  k_xproj<<<dim3(32, 2, 2), 256, 0, stream>>>(imgemb, wpf, wpb, bsf, bsb, xgf, xgb);

  // ---- BiLSTM: 1408 blocks x 16 rows (R5-proven, frozen) ----
  k_lstm5<<<dim3(1408, 1, 1), 512, 0, stream>>>(charsb, wpf, wpb, xgf, xgb, hsf, hsb);

  // ---- attention ----
  k_gemm_mfma<<<TT*NWRD/64, 512, 0, stream>>>(hsf, hsb, a1p, a1b, nullptr, a2w, sb,
                                              TT*NWRD, 256, 1);
  k_gemm_mfma<<<NWRD/64, 512, 0, stream>>>(hsf, hsb, a3p, a3b, echar, nullptr, sb,
                                           NWRD, 256, 3);

  // ---- loss ----
  k_loss<<<NB, 64, 0, stream>>>(pos_u, u_emb, vbuf, echar, negi, v_emb, part);
  k_final<<<1, 256, 0, stream>>>(part, (float*)d_out);
}

// Round 10
// 210.611 us; speedup vs baseline: 1.0191x; 1.0191x over previous
//
#include <hip/hip_runtime.h>
#include <math.h>

// ---------------- model dims ----------------
#define NIMG   2048
#define EMB    128
#define NB     1024
#define WCTX   6
#define CPW    5
#define NEG    5
#define MNOISE 512
#define NWRD   11264
#define NPOSW  6144
#define TT     5

typedef __bf16 bf16x8 __attribute__((ext_vector_type(8)));
typedef float  f32x4  __attribute__((ext_vector_type(4)));
typedef float  f32x16 __attribute__((ext_vector_type(16)));

__device__ __forceinline__ float sigf(float x){ return __fdividef(1.0f, 1.0f+__expf(-x)); }
__device__ __forceinline__ float ftanh(float x){
  float xc = fminf(15.f, fmaxf(-15.f, x));
  float t = __expf(2.f*xc);
  return __fdividef(t - 1.f, t + 1.f);
}
__device__ __forceinline__ float splus(float z){
  return (z > 0.0f) ? z + log1pf(expf(-z)) : log1pf(expf(z));
}
__device__ __forceinline__ float clip10(float x){ return fminf(10.0f, fmaxf(-10.0f, x)); }
__device__ __forceinline__ float wsum64(float v){
  #pragma unroll
  for (int m = 1; m < 64; m <<= 1) v += __shfl_xor(v, m);
  return v;
}
__device__ __forceinline__ unsigned short f2b(float x){
  union { float f; unsigned u; } v; v.f = x;
  unsigned r = v.u + 0x7fff + ((v.u >> 16) & 1);
  return (unsigned short)(r >> 16);
}
__device__ __forceinline__ float b2f(unsigned short h){
  union { unsigned u; float f; } v; v.u = ((unsigned)h) << 16; return v.f;
}
__device__ __forceinline__ bf16x8 as_bf(uint4 u){
  union { uint4 q; bf16x8 v; } c; c.q = u; return c.v;
}

// ---------------- mega prep ----------------
__global__ void k_prep(
  const float* __restrict__ wi_f, const float* __restrict__ wh_f,
  const float* __restrict__ wi_b, const float* __restrict__ wh_b,
  const float* __restrict__ a1w, const float* __restrict__ a3w,
  const float* __restrict__ c2w,
  const float* __restrict__ bi_f, const float* __restrict__ bh_f,
  const float* __restrict__ bi_b, const float* __restrict__ bh_b,
  const float* __restrict__ a2b, const float* __restrict__ v_emb,
  const int* __restrict__ pos_v, const int* __restrict__ w2c,
  unsigned short* __restrict__ wpf, unsigned short* __restrict__ wpb,
  unsigned short* __restrict__ a1p, unsigned short* __restrict__ a3p,
  unsigned short* __restrict__ c2p,
  float* __restrict__ bsf, float* __restrict__ bsb, float* __restrict__ sbuf,
  float* __restrict__ vbuf, float* __restrict__ vnorm,
  int* __restrict__ chars, float* __restrict__ st, float* __restrict__ scacc,
  float* __restrict__ fcout, float* __restrict__ norms2, int nvocab)
{
  int id = blockIdx.x*256 + threadIdx.x;
  if (id < 262144){
    int dir = id >> 17;
    int lid = id & 131071;
    const float* wi = dir ? wi_b : wi_f;
    const float* wh = dir ? wh_b : wh_f;
    unsigned short* out = dir ? wpb : wpf;
    int j = lid&7, l = (lid>>3)&63, p = (lid>>9)&31, s = lid>>14;
    int wn = p>>3, nf = p&7;
    int gate = nf&3, jb = wn*2 + (nf>>2);
    int n = gate*128 + jb*16 + (l&15);
    int k = s*32 + ((l>>4)<<3) + j;
    float v = (k < 128) ? wi[n*128+k] : wh[n*128 + (k-128)];
    out[lid] = f2b(v);
  } else if (id < 327680){
    int lid = id - 262144;
    int seg = lid >> 15;
    int pid = lid & 32767;
    const float* W = seg ? a3w : a1w;
    unsigned short* out = seg ? a3p : a1p;
    int j = pid&7, l = (pid>>3)&63, rest = pid>>9;
    int p = rest & 7, s = rest >> 3;
    int n = p*16 + (l&15);
    int k = s*32 + ((l>>4)<<3) + j;
    out[pid] = f2b(W[n*256 + k]);
  } else if (id < 336896){
    int pid = id - 327680;
    int j = pid & 7, l = (pid >> 3) & 63, p = (pid >> 9) & 1, t9 = pid >> 10;
    int oc = p*16 + (l & 15), ic = ((l >> 4) << 3) + j;
    c2p[pid] = f2b(c2w[oc*288 + ic*9 + t9]);
  } else if (id < 337408){
    int i = id - 336896;
    bsf[i] = bi_f[i] + bh_f[i];
    bsb[i] = bi_b[i] + bh_b[i];
  } else if (id < 393728){
    int i = id - 337408;
    sbuf[i] = a2b[0];
  } else if (id < 459264){
    int b = (id - 393728) >> 6;
    int l = id & 63;
    float s0 = 0.f, s1 = 0.f;
    for (int w = 0; w < WCTX; w++){
      int vid = pos_v[b*WCTX + w];
      s0 += v_emb[(size_t)vid*128 + l];
      s1 += v_emb[(size_t)vid*128 + 64 + l];
    }
    s0 *= (1.f/6.f); s1 *= (1.f/6.f);
    vbuf[b*128 + l] = s0; vbuf[b*128 + 64 + l] = s1;
    float nn = wsum64(s0*s0 + s1*s1);
    if (l == 0) vnorm[b] = sqrtf(nn);
  } else if (id < 489984){
    int i = id - 459264;
    int wi_ = i / CPW, t = i - wi_*CPW;
    chars[i] = w2c[pos_v[wi_]*CPW + t];
  } else if (id < 491008){
    st[id - 489984] = 0.f;
  } else if (id < 494464){
    scacc[id - 491008] = 0.f;
  } else if (id < 756608){
    fcout[id - 494464] = 0.f;
  } else if (id < 1556608){
    int lid = id - 756608;
    int row = lid >> 4, s = id & 15;
    if (row < nvocab){
      const float4* vp = (const float4*)(v_emb + (size_t)row*128 + s*8);
      float4 x0 = vp[0], x1 = vp[1];
      float q = x0.x*x0.x + x0.y*x0.y + x0.z*x0.z + x0.w*x0.w
              + x1.x*x1.x + x1.y*x1.y + x1.z*x1.z + x1.w*x1.w;
      q += __shfl_xor(q, 1); q += __shfl_xor(q, 2);
      q += __shfl_xor(q, 4); q += __shfl_xor(q, 8);
      if (s == 0) norms2[row] = q;
    }
  }
}

// ---------------- conv1 stats: 4 images per block ----------------
__global__ __launch_bounds__(256) void k_stats1(
    const float* __restrict__ img, float* __restrict__ SC)
{
  __shared__ float im[1444];
  __shared__ float SCw[4][54];
  int tid = threadIdx.x;
  float S[9], C[45];
  #pragma unroll
  for (int a = 0; a < 9; a++) S[a] = 0.f;
  #pragma unroll
  for (int a = 0; a < 45; a++) C[a] = 0.f;
  for (int ii = 0; ii < 4; ii++){
    int n = blockIdx.x*4 + ii;
    const float* ip = img + (size_t)n*1444;
    __syncthreads();
    for (int i = tid; i < 1444; i += 256) im[i] = ip[i];
    __syncthreads();
    for (int p = tid; p < 1296; p += 256){
      int oh = p/36, ow = p - oh*36;
      float P[9];
      #pragma unroll
      for (int i = 0; i < 3; i++)
        #pragma unroll
        for (int j = 0; j < 3; j++)
          P[i*3+j] = im[(oh+i)*38 + ow + j];
      int idx = 0;
      #pragma unroll
      for (int a = 0; a < 9; a++){
        S[a] += P[a];
        #pragma unroll
        for (int b = a; b < 9; b++){ C[idx] += P[a]*P[b]; idx++; }
      }
    }
  }
  #pragma unroll
  for (int a = 0; a < 9; a++) S[a] = wsum64(S[a]);
  #pragma unroll
  for (int a = 0; a < 45; a++) C[a] = wsum64(C[a]);
  if ((tid & 63) == 0){
    int w = tid >> 6;
    #pragma unroll
    for (int a = 0; a < 9; a++) SCw[w][a] = S[a];
    #pragma unroll
    for (int a = 0; a < 45; a++) SCw[w][9+a] = C[a];
  }
  __syncthreads();
  if (tid < 54){
    float v = SCw[0][tid] + SCw[1][tid] + SCw[2][tid] + SCw[3][tid];
    atomicAdd(&SC[tid*64 + (blockIdx.x & 63)], v);
  }
}

// ---------------- BN1 finalize + fold into conv1 weights/bias ----------------
// also zeroes the stp partial buffer for k_conv12 (runs right before it)
__global__ void k_fold1(const float* __restrict__ SC, const float* __restrict__ c1w,
                        const float* __restrict__ c1b, const float* __restrict__ g1,
                        const float* __restrict__ b1,
                        unsigned short* __restrict__ c1p, float* __restrict__ bias1c,
                        float* __restrict__ stp)
{
  __shared__ float S[9], C[45];
  __shared__ float scs[32];
  int tid = threadIdx.x;   // 64
  #pragma unroll
  for (int k = 0; k < 64; k++) stp[k*64 + tid] = 0.f;
  if (tid < 54){
    float acc = 0.f;
    for (int s = 0; s < 64; s++) acc += SC[tid*64 + s];
    if (tid < 9) S[tid] = acc; else C[tid-9] = acc;
  }
  __syncthreads();
  if (tid < 32){
    const float invN = 1.0f/2654208.0f;
    float w[9];
    #pragma unroll
    for (int a = 0; a < 9; a++) w[a] = c1w[tid*9+a];
    float b = c1b[tid];
    float sum = 0.f;
    #pragma unroll
    for (int a = 0; a < 9; a++) sum += w[a]*S[a];
    float sq = 0.f; int idx = 0;
    #pragma unroll
    for (int a = 0; a < 9; a++)
      #pragma unroll
      for (int bb_ = a; bb_ < 9; bb_++){
        float f = (bb_ == a) ? w[a]*w[a] : 2.f*w[a]*w[bb_];
        sq += f*C[idx]; idx++;
      }
    float Epre = sum*invN;
    float var = sq*invN - Epre*Epre;
    float m = Epre + b;
    float sc = g1[tid]*rsqrtf(var + 1e-5f);
    scs[tid] = sc;
    bias1c[tid] = sc*b + (b1[tid] - m*sc);
  }
  __syncthreads();
  {
    int l = tid;
    int ch = l & 31;
    float sc = scs[ch];
    #pragma unroll
    for (int j = 0; j < 8; j++){
      int k = ((l >> 5) << 3) + j;
      int kh = k >> 2, kw = k & 3;
      float v = (kh < 3 && kw < 3) ? c1w[ch*9 + kh*3 + kw]*sc : 0.f;
      c1p[l*8+j] = f2b(v);
    }
  }
}

// ---------------- fused conv1+conv2 ----------------
// R3 structure + spread BN2-stat atomics + bfr[9] hoisted to kernel start
// (latency hides under img staging + conv1; single temporal burst keeps
// c2pack L2-resident per the R4 lesson).
__global__ __launch_bounds__(512) void k_conv12(
    const float* __restrict__ img, const unsigned short* __restrict__ c1p,
    const float* __restrict__ bias1c, const unsigned short* __restrict__ c2pack,
    const float* __restrict__ c2b,
    unsigned short* __restrict__ flat2, float* __restrict__ stp)
{
  __shared__ __align__(16) unsigned short Ai[1520];
  __shared__ __align__(16) unsigned short Bi[1520];
  __shared__ __align__(16) unsigned short Pt[324*32];
  __shared__ float lsum[32], lsq[32];
  int n = blockIdx.x, tid = threadIdx.x;
  int l = tid & 63, w = tid >> 6;
  int wN = w & 1;
  bf16x8 bfr[9];
  #pragma unroll
  for (int t9 = 0; t9 < 9; t9++)
    bfr[t9] = as_bf(*(const uint4*)(c2pack + ((size_t)(t9*2 + wN)*64 + l)*8));
  if (tid < 190){
    int r = tid/5, c = tid - r*5;
    if (c < 2) Ai[r*40 + 38 + c] = 0;
    else       Bi[r*40 + 37 + (c-2)] = 0;
  }
  if (tid >= 192 && tid < 224){ lsum[tid-192] = 0.f; }
  if (tid >= 224 && tid < 256){ lsq[tid-224] = 0.f; }
  const float4* ip4 = (const float4*)(img + (size_t)n*1444);
  for (int i = tid; i < 361; i += 512){
    float4 v = ip4[i];
    int flat = i*4;
    const float* pv = (const float*)&v;
    #pragma unroll
    for (int e = 0; e < 4; e++){
      int f = flat + e;
      int r = f / 38, c = f - r*38;
      unsigned short h = f2b(pv[e]);
      Ai[r*40 + c] = h;
      if (c) Bi[r*40 + c - 1] = h;
    }
  }
  __syncthreads();
  {
    int hi = l >> 5;
    int ch = l & 31;
    int r31 = l & 31;
    int member = r31 & 3;
    const unsigned short* P = (member & 1) ? Bi : Ai;
    int rowoff = (member >> 1) * 40;
    bf16x8 bw = as_bf(*(const uint4*)(c1p + (size_t)l*8));
    float bias = bias1c[ch];
    int inoff = (ch & 7)*2;
    int chgrp = ch >> 3;
    #pragma unroll 2
    for (int g = w; g < 41; g += 8){
      int ql = g*8 + (r31 >> 2);
      if (ql > 323) ql = 323;
      int ph = ql/18, pw = ql - ph*18;
      int off = (2*ph)*40 + rowoff + 2*pw;
      uint4 a = (uint4){0u,0u,0u,0u};
      if (hi == 0){
        const unsigned* p0 = (const unsigned*)(P + off);
        const unsigned* p1 = (const unsigned*)(P + off + 40);
        a.x = p0[0]; a.y = p0[1]; a.z = p1[0]; a.w = p1[1];
      } else {
        const unsigned* p2 = (const unsigned*)(P + off + 80);
        a.x = p2[0]; a.y = p2[1];
      }
      f32x16 acc = __builtin_amdgcn_mfma_f32_32x32x16_bf16(
          as_bf(a), bw,
          (f32x16){0.f,0.f,0.f,0.f,0.f,0.f,0.f,0.f,0.f,0.f,0.f,0.f,0.f,0.f,0.f,0.f},
          0, 0, 0);
      #pragma unroll
      for (int rg = 0; rg < 4; rg++){
        int qo = g*8 + rg*2 + hi;
        if (qo < 324){
          float v0 = acc[rg*4+0]+bias, v1 = acc[rg*4+1]+bias;
          float v2 = acc[rg*4+2]+bias, v3 = acc[rg*4+3]+bias;
          float mx = fmaxf(fmaxf(v0,v1), fmaxf(v2,v3));
          *(unsigned short*)((char*)Pt + qo*64 + (((chgrp ^ (qo & 3)) << 4) + inoff)) = f2b(mx);
        }
      }
    }
  }
  __syncthreads();
  int wM = w >> 1;
  f32x4 acc[4];
  #pragma unroll
  for (int mf = 0; mf < 4; mf++) acc[mf] = (f32x4){0.f,0.f,0.f,0.f};
  #pragma unroll
  for (int t9 = 0; t9 < 9; t9++){
    int kh = t9/3, kw = t9 - (t9/3)*3;
    #pragma unroll
    for (int mf = 0; mf < 4; mf++){
      int pos = wM*64 + mf*16 + (l & 15);
      int oh = pos >> 4, ow = pos & 15;
      int q = (oh + kh)*18 + (ow + kw);
      int slot = ((l >> 4) ^ q) & 3;
      bf16x8 a = as_bf(*(const uint4*)((const char*)Pt + q*64 + slot*16));
      acc[mf] = __builtin_amdgcn_mfma_f32_16x16x32_bf16(a, bfr[t9], acc[mf], 0, 0, 0);
    }
  }
  int oc = wN*16 + (l & 15);
  int qq = l >> 4;
  float bb = c2b[oc];
  float vm[4][4];
  float s = 0.f, sq = 0.f;
  #pragma unroll
  for (int mf = 0; mf < 4; mf++)
    #pragma unroll
    for (int reg = 0; reg < 4; reg++){
      float v = acc[mf][reg] + bb;
      vm[mf][reg] = v;
      s += v; sq += v*v;
    }
  s += __shfl_xor(s,16); sq += __shfl_xor(sq,16);
  s += __shfl_xor(s,32); sq += __shfl_xor(sq,32);
  if (qq == 0){ atomicAdd(&lsum[oc], s); atomicAdd(&lsq[oc], sq); }
  unsigned short* fp = flat2 + (size_t)n*2048 + oc*64;
  #pragma unroll
  for (int mp = 0; mp < 2; mp++){
    int ph = wM*2 + mp;
    float p0 = fmaxf(fmaxf(vm[2*mp][0], vm[2*mp][1]), fmaxf(vm[2*mp+1][0], vm[2*mp+1][1]));
    float p1 = fmaxf(fmaxf(vm[2*mp][2], vm[2*mp][3]), fmaxf(vm[2*mp+1][2], vm[2*mp+1][3]));
    unsigned pk = ((unsigned)f2b(p1) << 16) | (unsigned)f2b(p0);
    *(unsigned*)(fp + ph*8 + qq*2) = pk;
  }
  __syncthreads();
  if (tid < 32){
    int slot = (blockIdx.x & 63)*64;
    atomicAdd(&stp[slot + tid], lsum[tid]);
    atomicAdd(&stp[slot + 32 + tid], lsq[tid]);
  }
}

// ---------------- fc pack with BN2 scale folded (+ inline 64-slot fold) ----------------
__global__ __launch_bounds__(256) void k_fcscale(const float* __restrict__ fcw,
                          const float* __restrict__ stp,
                          const float* __restrict__ g2, unsigned short* __restrict__ fcp)
{
  __shared__ float fs[64];
  int tid = threadIdx.x;
  if (tid < 64){
    float acc = 0.f;
    #pragma unroll 8
    for (int s = 0; s < 64; s++) acc += stp[s*64 + tid];
    fs[tid] = acc;
  }
  __syncthreads();
  int id = blockIdx.x*256 + tid;
  if (id >= 262144) return;
  int j = id&7, lq = (id>>3)&63, rest = id>>9;
  int p = rest & 7, sg = rest >> 3;
  int n = p*16 + (lq&15);
  int k = sg*32 + ((lq>>4)<<3) + j;
  int c = k >> 6;
  float m = fs[c]*(1.f/524288.f);
  float var = fs[32+c]*(1.f/524288.f) - m*m;
  float sc = g2[c]*rsqrtf(var + 1e-5f);
  fcp[id] = f2b(fcw[(size_t)n*2048 + k] * sc);
}

// ---------------- generic MFMA GEMM, N=128 ----------------
__global__ __launch_bounds__(512) void k_gemm_mfma(
    const unsigned short* __restrict__ A0, const unsigned short* __restrict__ A1,
    const unsigned short* __restrict__ wpack, const float* __restrict__ bias,
    float* __restrict__ out, const float* __restrict__ a2w, float* __restrict__ sbuf,
    int M, int K, int fuse)
{
  __shared__ unsigned short At[64*256];
  __shared__ float wt[64][5];
  int tid = threadIdx.x;
  int l = tid & 63, wid = tid >> 6;
  int row0 = blockIdx.x * 64;
  int wm = wid >> 2, wn = wid & 3;
  int kspan = K / gridDim.y;
  int kbeg = blockIdx.y * kspan;
  f32x4 acc[2][2];
  #pragma unroll
  for (int a = 0; a < 2; a++)
    #pragma unroll
    for (int b = 0; b < 2; b++) acc[a][b] = (f32x4){0.f,0.f,0.f,0.f};

  if (fuse == 3){
    if (tid < 64){
      int gr = row0 + tid;
      float sv[TT];
      float mx = -1e30f;
      #pragma unroll
      for (int t = 0; t < TT; t++){ sv[t] = sbuf[t*NWRD + gr]; mx = fmaxf(mx, sv[t]); }
      float sum = 0.f;
      #pragma unroll
      for (int t = 0; t < TT; t++){ sv[t] = __expf(sv[t] - mx); sum += sv[t]; }
      float inv = __fdividef(1.f, sum);
      #pragma unroll
      for (int t = 0; t < TT; t++) wt[tid][t] = sv[t]*inv;
    }
    __syncthreads();
  }

  for (int kc = kbeg; kc < kbeg + kspan; kc += 256){
    #pragma unroll
    for (int it = 0; it < 4; it++){
      int ci = tid + 512*it;
      int r = ci >> 5, c = ci & 31;
      int gr = row0 + r; int k = kc + c*8;
      uint4 v;
      if (fuse == 3){
        int col = (k < 128) ? k : (k - 128);
        const unsigned short* sp = (k < 128) ? A0 : A1;
        float a8[8];
        #pragma unroll
        for (int e = 0; e < 8; e++) a8[e] = 0.f;
        #pragma unroll
        for (int t = 0; t < TT; t++){
          uint4 hv = *(const uint4*)(sp + ((size_t)t*NWRD + gr)*128 + col);
          const unsigned short* ph = (const unsigned short*)&hv;
          float wgt = wt[r][t];
          #pragma unroll
          for (int e = 0; e < 8; e++) a8[e] += wgt * b2f(ph[e]);
        }
        unsigned short o[8];
        #pragma unroll
        for (int e = 0; e < 8; e++) o[e] = f2b(a8[e]);
        v = *(uint4*)o;
      } else {
        const unsigned short* src;
        if (A1) src = (k < 128) ? (A0 + (size_t)gr*128 + k) : (A1 + (size_t)gr*128 + (k-128));
        else    src = A0 + (size_t)gr*K + k;
        v = *(const uint4*)src;
      }
      *(uint4*)((char*)At + r*512 + ((c*16) ^ ((r & 7) << 4))) = v;
    }
    __syncthreads();
    #pragma unroll
    for (int s8 = 0; s8 < 8; s8++){
      int s = (kc >> 5) + s8;
      bf16x8 af[2];
      #pragma unroll
      for (int mf = 0; mf < 2; mf++){
        int r = wm*32 + mf*16 + (l & 15);
        int cb = (s8*4 + (l >> 4)) ^ (r & 7);
        af[mf] = as_bf(*(const uint4*)((const char*)At + r*512 + cb*16));
      }
      #pragma unroll
      for (int nf = 0; nf < 2; nf++){
        bf16x8 bf_ = as_bf(*(const uint4*)(wpack + ((size_t)(s*8 + wn*2 + nf)*64 + l)*8));
        acc[0][nf] = __builtin_amdgcn_mfma_f32_16x16x32_bf16(af[0], bf_, acc[0][nf], 0,0,0);
        acc[1][nf] = __builtin_amdgcn_mfma_f32_16x16x32_bf16(af[1], bf_, acc[1][nf], 0,0,0);
      }
    }
    __syncthreads();
  }
  if (fuse == 0 || fuse == 3){
    #pragma unroll
    for (int mf = 0; mf < 2; mf++)
      #pragma unroll
      for (int nf = 0; nf < 2; nf++)
        #pragma unroll
        for (int reg = 0; reg < 4; reg++){
          int row = row0 + wm*32 + mf*16 + ((l >> 4) << 2) + reg;
          int col = wn*32 + nf*16 + (l & 15);
          out[(size_t)row*128 + col] = acc[mf][nf][reg] + bias[col];
        }
  } else if (fuse == 2){
    #pragma unroll
    for (int mf = 0; mf < 2; mf++)
      #pragma unroll
      for (int nf = 0; nf < 2; nf++)
        #pragma unroll
        for (int reg = 0; reg < 4; reg++){
          int row = row0 + wm*32 + mf*16 + ((l >> 4) << 2) + reg;
          int col = wn*32 + nf*16 + (l & 15);
          atomicAdd(&out[(size_t)row*128 + col], acc[mf][nf][reg]);
        }
  } else {
    float part[2][4];
    #pragma unroll
    for (int mf = 0; mf < 2; mf++)
      #pragma unroll
      for (int reg = 0; reg < 4; reg++){
        float p = 0.f;
        #pragma unroll
        for (int nf = 0; nf < 2; nf++){
          int col = wn*32 + nf*16 + (l & 15);
          p += ftanh(acc[mf][nf][reg] + bias[col]) * a2w[col];
        }
        part[mf][reg] = p;
      }
    #pragma unroll
    for (int msk = 1; msk < 16; msk <<= 1)
      #pragma unroll
      for (int mf = 0; mf < 2; mf++)
        #pragma unroll
        for (int reg = 0; reg < 4; reg++)
          part[mf][reg] += __shfl_xor(part[mf][reg], msk);
    if ((l & 15) == 0){
      #pragma unroll
      for (int mf = 0; mf < 2; mf++)
        #pragma unroll
        for (int reg = 0; reg < 4; reg++)
          atomicAdd(&sbuf[row0 + wm*32 + mf*16 + ((l >> 4) << 2) + reg], part[mf][reg]);
    }
  }
}

// ---------------- BN1d fused ----------------
__global__ __launch_bounds__(256) void k_bn1d_fused(const float* __restrict__ fc,
    const float* __restrict__ g3, const float* __restrict__ b3,
    unsigned short* __restrict__ img_emb)
{
  int j = blockIdx.x, tid = threadIdx.x;
  float vr[8];
  float s = 0.f, q = 0.f;
  #pragma unroll
  for (int u = 0; u < 8; u++){
    float v = fc[(u*256 + tid)*128 + j];
    vr[u] = v; s += v; q += v*v;
  }
  s = wsum64(s); q = wsum64(q);
  __shared__ float rs[4], rq[4];
  if ((tid & 63) == 0){ rs[tid>>6] = s; rq[tid>>6] = q; }
  __syncthreads();
  float S = rs[0]+rs[1]+rs[2]+rs[3];
  float Q = rq[0]+rq[1]+rq[2]+rq[3];
  float m = S*(1.f/2048.f);
  float var = Q*(1.f/2048.f) - m*m;
  float sc = g3[j]*rsqrtf(var + 1e-5f);
  float sh = b3[j] - m*sc;
  #pragma unroll
  for (int u = 0; u < 8; u++)
    img_emb[(u*256 + tid)*128 + j] = f2b(fmaxf(0.f, vr[u]*sc + sh));
}

// ---------------- LSTM x-projection -> bf16 packed gates ----------------
__global__ __launch_bounds__(256) void k_xproj(
    const unsigned short* __restrict__ xemb,
    const unsigned short* __restrict__ wpf, const unsigned short* __restrict__ wpb,
    const float* __restrict__ bsf, const float* __restrict__ bsb,
    unsigned short* __restrict__ xgf, unsigned short* __restrict__ xgb)
{
  __shared__ unsigned short At[64*128];
  int dir = blockIdx.z;
  const unsigned short* wpack = dir ? wpb : wpf;
  const float* bsum = dir ? bsb : bsf;
  unsigned short* xg = dir ? xgb : xgf;
  int tid = threadIdx.x;
  int l = tid & 63, wid = tid >> 6;
  int row0 = blockIdx.x * 64;
  int wm = wid >> 1;
  int wn = blockIdx.y*2 + (wid & 1);
  #pragma unroll
  for (int it = 0; it < 4; it++){
    int ci = tid + 256*it;
    int r = ci >> 4, c = ci & 15;
    uint4 v = *(const uint4*)(xemb + (size_t)(row0 + r)*128 + c*8);
    *(uint4*)((char*)At + r*256 + ((c*16) ^ ((r & 7) << 4))) = v;
  }
  __syncthreads();
  f32x4 acc[2][8];
  #pragma unroll
  for (int a = 0; a < 2; a++)
    #pragma unroll
    for (int b = 0; b < 8; b++) acc[a][b] = (f32x4){0.f,0.f,0.f,0.f};
  #pragma unroll
  for (int s4 = 0; s4 < 4; s4++){
    bf16x8 af[2];
    #pragma unroll
    for (int mf = 0; mf < 2; mf++){
      int r = wm*32 + mf*16 + (l & 15);
      int cb = (s4*4 + (l >> 4)) ^ (r & 7);
      af[mf] = as_bf(*(const uint4*)((const char*)At + r*256 + cb*16));
    }
    #pragma unroll
    for (int nf = 0; nf < 8; nf++){
      bf16x8 bf_ = as_bf(*(const uint4*)(wpack + ((size_t)(s4*32 + wn*8 + nf)*64 + l)*8));
      acc[0][nf] = __builtin_amdgcn_mfma_f32_16x16x32_bf16(af[0], bf_, acc[0][nf], 0,0,0);
      acc[1][nf] = __builtin_amdgcn_mfma_f32_16x16x32_bf16(af[1], bf_, acc[1][nf], 0,0,0);
    }
  }
  #pragma unroll
  for (int mf = 0; mf < 2; mf++)
    #pragma unroll
    for (int reg = 0; reg < 4; reg++){
      int gr = row0 + wm*32 + mf*16 + ((l >> 4) << 2) + reg;
      unsigned short* xrow = xg + (size_t)gr*512;
      #pragma unroll
      for (int js = 0; js < 2; js++){
        int jl = wn*32 + js*16 + (l & 15);
        unsigned short o[4];
        o[0] = f2b(acc[mf][js*4+0][reg] + bsum[jl]);
        o[1] = f2b(acc[mf][js*4+1][reg] + bsum[128+jl]);
        o[2] = f2b(acc[mf][js*4+2][reg] + bsum[256+jl]);
        o[3] = f2b(acc[mf][js*4+3][reg] + bsum[384+jl]);
        *(uint2*)(xrow + jl*4) = *(uint2*)o;
      }
    }
}

// ---------------- fused 5-step dual-direction LSTM ----------------
// R5-proven version (46.6us), FROZEN: 1408 blocks x one 16-row tile; hh
// weights register-resident (16 frags = 64 VGPR, 8 waves/SIMD); post-barrier
// prefetch of next-step xv gathers; nontemporal hs flush; med3 clamps.
// R6/R7: widening per-block work loses (VGPR >64 halves waves/SIMD).
__global__ __launch_bounds__(512, 4) void k_lstm5(
    const int* __restrict__ chars,
    const unsigned short* __restrict__ wpf, const unsigned short* __restrict__ wpb,
    const unsigned short* __restrict__ xgf, const unsigned short* __restrict__ xgb,
    unsigned short* __restrict__ hsf, unsigned short* __restrict__ hsb)
{
  __shared__ __align__(16) unsigned short At[2][2048];   // 2 x 4KB swizzled h tiles
  __shared__ int cid_s[80];                               // 16 rows x 5 steps
  int b = blockIdx.x;
  int br = b & 7;
  int dir = br >> 2;
  int rblk = (b >> 3)*4 + (br & 3);        // 0..703 per dir
  const unsigned short* wpack = dir ? wpb : wpf;
  const unsigned short* xg = dir ? xgb : xgf;
  unsigned short* hs = dir ? hsb : hsf;
  int tid = threadIdx.x;
  int l = tid & 63, c = tid >> 6;          // c = 16-col h-slice 0..7
  int jl = c*16 + (l & 15);                // global h column
  int row0 = rblk * 16;

  if (tid < 80) cid_s[tid] = chars[row0*CPW + tid];

  bf16x8 wreg[4][4];
  #pragma unroll
  for (int s4 = 0; s4 < 4; s4++)
    #pragma unroll
    for (int g = 0; g < 4; g++)
      wreg[s4][g] = as_bf(*(const uint4*)(wpack + ((size_t)((s4+4)*32 + c*4 + g)*64 + l)*8));

  int frow = tid >> 5, fq = tid & 31;
  int fof = (((fq >> 1) ^ (frow & 7)) << 4) | ((fq & 1) << 3);

  __syncthreads();                          // cid_s ready

  int rbase = (l >> 4) << 2;
  int t0 = dir ? (TT-1) : 0;
  uint2 xv[4], xvn[4];
  #pragma unroll
  for (int reg = 0; reg < 4; reg++)
    xv[reg] = *(const uint2*)(xg + (size_t)cid_s[(rbase+reg)*CPW + t0]*512 + jl*4);

  float creg[4];
  #pragma unroll
  for (int reg = 0; reg < 4; reg++) creg[reg] = 0.f;
  int tprev = t0;

  #pragma unroll
  for (int tF = 0; tF < TT; tF++){
    int t = dir ? (TT-1-tF) : tF;
    f32x4 acc[4];
    if (tF > 0){
      __syncthreads();
      const unsigned short* buf = At[(tF-1) & 1];
      uint2 hv = *(const uint2*)((const char*)buf + tid*8);
      {
        union { uint2 v; unsigned long long q; } cv; cv.v = hv;
        __builtin_nontemporal_store(cv.q,
          (unsigned long long*)((char*)(hs + (size_t)tprev*NWRD*128 + (size_t)(row0 + frow)*128) + fof));
      }
      if (tF + 1 < TT){
        int tn = dir ? (TT-2-tF) : (tF+1);
        #pragma unroll
        for (int reg = 0; reg < 4; reg++)
          xvn[reg] = *(const uint2*)(xg + (size_t)cid_s[(rbase+reg)*CPW + tn]*512 + jl*4);
      }
      #pragma unroll
      for (int g = 0; g < 4; g++) acc[g] = (f32x4){0.f,0.f,0.f,0.f};
      #pragma unroll
      for (int s4 = 0; s4 < 4; s4++){
        int r = l & 15;
        int cb = (s4*4 + (l >> 4)) ^ (r & 7);
        bf16x8 af = as_bf(*(const uint4*)((const char*)buf + r*256 + cb*16));
        #pragma unroll
        for (int g = 0; g < 4; g++)
          acc[g] = __builtin_amdgcn_mfma_f32_16x16x32_bf16(af, wreg[s4][g], acc[g], 0,0,0);
      }
    } else {
      int tn = dir ? (TT-2) : 1;
      #pragma unroll
      for (int reg = 0; reg < 4; reg++)
        xvn[reg] = *(const uint2*)(xg + (size_t)cid_s[(rbase+reg)*CPW + tn]*512 + jl*4);
      #pragma unroll
      for (int g = 0; g < 4; g++) acc[g] = (f32x4){0.f,0.f,0.f,0.f};
    }
    unsigned short* wb = At[tF & 1];
    #pragma unroll
    for (int reg = 0; reg < 4; reg++){
      int rloc = ((l >> 4) << 2) + reg;
      const unsigned short* xs = (const unsigned short*)&xv[reg];
      float ig = acc[0][reg] + b2f(xs[0]);
      float fg = acc[1][reg] + b2f(xs[1]);
      float gg = acc[2][reg] + b2f(xs[2]);
      float og = acc[3][reg] + b2f(xs[3]);
      float co = creg[reg];
      float ei = __expf(-__builtin_amdgcn_fmed3f(ig, -30.f, 30.f));
      float eg = __expf(2.f*__builtin_amdgcn_fmed3f(gg, -15.f, 15.f));
      float sf = __fdividef(1.f, 1.f + __expf(-__builtin_amdgcn_fmed3f(fg, -30.f, 30.f)));
      float itg = __fdividef(eg - 1.f, (1.f + ei)*(eg + 1.f));
      float cn = sf*co + itg;
      float eo = __expf(-__builtin_amdgcn_fmed3f(og, -30.f, 30.f));
      float ec = __expf(2.f*__builtin_amdgcn_fmed3f(cn, -15.f, 15.f));
      float h  = __fdividef(ec - 1.f, (1.f + eo)*(ec + 1.f));
      creg[reg] = cn;
      int byteoff = rloc*256 + ((((jl >> 3) << 4) ^ ((rloc & 7) << 4)) + (jl & 7)*2);
      *(unsigned short*)((char*)wb + byteoff) = f2b(h);
    }
    tprev = t;
    #pragma unroll
    for (int reg = 0; reg < 4; reg++) xv[reg] = xvn[reg];
  }
  __syncthreads();
  const unsigned short* buf = At[(TT-1) & 1];
  uint2 hv = *(const uint2*)((const char*)buf + tid*8);
  {
    union { uint2 v; unsigned long long q; } cv; cv.v = hv;
    __builtin_nontemporal_store(cv.q,
      (unsigned long long*)((char*)(hs + (size_t)tprev*NWRD*128 + (size_t)(row0 + frow)*128) + fof));
  }
}

// ---------------- cosine sims (grid.y = 4; R8-proven split version) ----------------
__global__ __launch_bounds__(256) void k_cos2(const int* __restrict__ noise,
    const float* __restrict__ v_emb, const float* __restrict__ vbuf,
    const float* __restrict__ vnorm, const float* __restrict__ norms2,
    float* __restrict__ cosb)
{
  int b = blockIdx.x;
  int tid = threadIdx.x;
  int s = tid & 15;
  int rsub = (tid >> 4) & 3;
  int wid = tid >> 6;
  const float4* ep = (const float4*)(vbuf + b*128 + s*8);
  float4 e0 = ep[0], e1 = ep[1];
  float nb = vnorm[b];
  int mbase = blockIdx.y*128 + wid*4 + rsub;
  #pragma unroll 4
  for (int iter = 0; iter < 8; iter++){
    int m = mbase + iter*16;
    int id = noise[b*MNOISE + m];
    const float4* vp = (const float4*)(v_emb + (size_t)id*128 + s*8);
    float4 x0 = vp[0], x1 = vp[1];
    float d = e0.x*x0.x + e0.y*x0.y + e0.z*x0.z + e0.w*x0.w
            + e1.x*x1.x + e1.y*x1.y + e1.z*x1.z + e1.w*x1.w;
    d += __shfl_xor(d, 1); d += __shfl_xor(d, 2);
    d += __shfl_xor(d, 4); d += __shfl_xor(d, 8);
    if (s == 0){
      float q = norms2[id];
      cosb[b*MNOISE + m] = d / fmaxf(nb*sqrtf(q), 1e-8f);
    }
  }
}

// ---------------- top-5 + negative char gather ----------------
__global__ __launch_bounds__(64) void k_topk(const float* __restrict__ cosb,
    const int* __restrict__ noise, const int* __restrict__ w2c,
    int* __restrict__ neg_ids, int* __restrict__ chars)
{
  __shared__ int nid_s[NEG];
  int b = blockIdx.x, l = threadIdx.x;
  float v[8];
  int base = b*MNOISE;
  #pragma unroll
  for (int q = 0; q < 8; q++) v[q] = cosb[base + l + 64*q];
  for (int r = 0; r < NEG; r++){
    float bv = -1e30f; int bidx = 1<<30;
    #pragma unroll
    for (int q = 0; q < 8; q++){
      int idx = l + 64*q;
      if (v[q] > bv || (v[q] == bv && idx < bidx)){ bv = v[q]; bidx = idx; }
    }
    #pragma unroll
    for (int m = 1; m < 64; m <<= 1){
      float ov = __shfl_xor(bv, m);
      int   oi = __shfl_xor(bidx, m);
      if (ov > bv || (ov == bv && oi < bidx)){ bv = ov; bidx = oi; }
    }
    if (l == 0){
      int nid = noise[base + bidx];
      neg_ids[b*NEG + r] = nid;
      nid_s[r] = nid;
    }
    int qsel = bidx >> 6;
    #pragma unroll
    for (int q = 0; q < 8; q++)
      if (q == qsel && (bidx & 63) == l) v[q] = -1e30f;
  }
  __syncthreads();
  if (l < NEG*CPW){
    int k = l / CPW, t = l - k*CPW;
    chars[(NPOSW + b*NEG + k)*CPW + t] = w2c[nid_s[k]*CPW + t];
  }
}

// ---------------- loss ----------------
__global__ __launch_bounds__(64) void k_loss(const int* __restrict__ pos_u,
    const float* __restrict__ u_emb, const float* __restrict__ vbuf,
    const float* __restrict__ echar, const int* __restrict__ neg_ids,
    const float* __restrict__ v_emb, float* __restrict__ part)
{
  int b = blockIdx.x, l = threadIdx.x;
  int pu = pos_u[b];
  float eu0 = u_emb[pu*128 + l], eu1 = u_emb[pu*128 + 64 + l];
  float c0 = 0.f, c1 = 0.f;
  for (int w = 0; w < WCTX; w++){
    int r = b*WCTX + w;
    c0 += echar[r*128 + l]; c1 += echar[r*128 + 64 + l];
  }
  c0 *= (1.f/6.f); c1 *= (1.f/6.f);
  float d1 = wsum64(eu0*c0 + eu1*c1);
  float d2 = wsum64(eu0*vbuf[b*128 + l] + eu1*vbuf[b*128 + 64 + l]);
  float tot = splus(-clip10(d1)) + splus(-clip10(d2));
  for (int k = 0; k < NEG; k++){
    int r = NPOSW + b*NEG + k;
    float dc = wsum64(eu0*echar[r*128 + l] + eu1*echar[r*128 + 64 + l]);
    int nid = neg_ids[b*NEG + k];
    float dn = wsum64(eu0*v_emb[nid*128 + l] + eu1*v_emb[nid*128 + 64 + l]);
    tot += splus(clip10(dc)) + splus(clip10(dn));
  }
  if (l == 0) part[b] = tot;
}

__global__ __launch_bounds__(256) void k_final(const float* __restrict__ part, float* __restrict__ out)
{
  int tid = threadIdx.x;
  float s = part[tid] + part[tid+256] + part[tid+512] + part[tid+768];
  s = wsum64(s);
  __shared__ float r[4];
  if ((tid & 63) == 0) r[tid>>6] = s;
  __syncthreads();
  if (tid == 0) out[0] = (r[0]+r[1]+r[2]+r[3]) * (1.0f/1024.0f);
}

// ---------------- launch ----------------
extern "C" void kernel_launch(void* const* d_in, const int* in_sizes, int n_in,
                              void* d_out, int out_size, void* d_ws, size_t ws_size,
                              hipStream_t stream)
{
  (void)n_in; (void)out_size; (void)ws_size;
  const int*   pos_u  = (const int*)  d_in[0];
  const int*   pos_v  = (const int*)  d_in[1];
  const int*   noise  = (const int*)  d_in[2];
  const int*   w2c    = (const int*)  d_in[3];
  const float* img    = (const float*)d_in[4];
  const float* u_emb  = (const float*)d_in[5];
  const float* v_emb  = (const float*)d_in[6];
  const float* c1w    = (const float*)d_in[7];
  const float* c1b    = (const float*)d_in[8];
  const float* g1     = (const float*)d_in[9];
  const float* b1     = (const float*)d_in[10];
  const float* c2w    = (const float*)d_in[11];
  const float* c2b    = (const float*)d_in[12];
  const float* g2     = (const float*)d_in[13];
  const float* b2     = (const float*)d_in[14];
  const float* fcw    = (const float*)d_in[15];
  const float* fcb    = (const float*)d_in[16];
  const float* g3     = (const float*)d_in[17];
  const float* b3     = (const float*)d_in[18];
  const float* wi_f   = (const float*)d_in[19];
  const float* wh_f   = (const float*)d_in[20];
  const float* bi_f   = (const float*)d_in[21];
  const float* bh_f   = (const float*)d_in[22];
  const float* wi_b   = (const float*)d_in[23];
  const float* wh_b   = (const float*)d_in[24];
  const float* bi_b   = (const float*)d_in[25];
  const float* bh_b   = (const float*)d_in[26];
  const float* a1w    = (const float*)d_in[27];
  const float* a1b    = (const float*)d_in[28];
  const float* a2w    = (const float*)d_in[29];
  const float* a2b    = (const float*)d_in[30];
  const float* a3w    = (const float*)d_in[31];
  const float* a3b    = (const float*)d_in[32];
  (void)fcb; (void)b2;
  int nvocab = in_sizes[6] / 128;

  char* ws = (char*)d_ws;
  typedef unsigned short u16;
  constexpr size_t OFF_ST   = 0;
  constexpr size_t OFF_WPF  = 4096;
  constexpr size_t OFF_WPB  = OFF_WPF + 262144;
  constexpr size_t OFF_A1P  = OFF_WPB + 262144;
  constexpr size_t OFF_A3P  = OFF_A1P + 65536;
  constexpr size_t OFF_FCP  = OFF_A3P + 65536;
  constexpr size_t OFF_C2P  = OFF_FCP + 524288;
  constexpr size_t OFF_C1P  = OFF_C2P + 18432;
  constexpr size_t OFF_BSF  = OFF_C1P + 2048;
  constexpr size_t OFF_BSB  = OFF_BSF + 2048;
  constexpr size_t OFF_SC   = OFF_BSB + 2048;
  constexpr size_t OFF_HSF  = OFF_SC + 14336;
  constexpr size_t OFF_HSB  = OFF_HSF + 14417920;
  constexpr size_t OFF_FL2  = OFF_HSB + 14417920;
  constexpr size_t OFF_ECH  = OFF_FL2 + 5767168;
  constexpr size_t OFF_FC   = OFF_ECH + 5767168;
  constexpr size_t OFF_IE   = OFF_FC  + 1048576;
  constexpr size_t OFF_VB   = OFF_IE  + 524288;
  constexpr size_t OFF_VN   = OFF_VB  + 524288;
  constexpr size_t OFF_COS  = OFF_VN  + 4096;
  constexpr size_t OFF_NI   = OFF_COS + 2097152;
  constexpr size_t OFF_CH   = OFF_NI  + 20480;
  constexpr size_t OFF_SB   = OFF_CH  + 225280;
  constexpr size_t OFF_PART = OFF_SB  + 225280;
  constexpr size_t OFF_NRM  = OFF_PART + 4096;
  constexpr size_t OFF_XGF  = OFF_NRM + 204800;
  constexpr size_t OFF_XGB  = OFF_XGF + 2097152;

  float* st      = (float*)(ws + OFF_ST);
  u16*   wpf     = (u16*)  (ws + OFF_WPF);
  u16*   wpb     = (u16*)  (ws + OFF_WPB);
  u16*   a1p     = (u16*)  (ws + OFF_A1P);
  u16*   a3p     = (u16*)  (ws + OFF_A3P);
  u16*   fcp     = (u16*)  (ws + OFF_FCP);
  u16*   c2p     = (u16*)  (ws + OFF_C2P);
  u16*   c1p     = (u16*)  (ws + OFF_C1P);
  float* bsf     = (float*)(ws + OFF_BSF);
  float* bsb     = (float*)(ws + OFF_BSB);
  float* scacc   = (float*)(ws + OFF_SC);
  u16*   flat2   = (u16*)  (ws + OFF_FL2);
  float* fcout   = (float*)(ws + OFF_FC);
  u16*   imgemb  = (u16*)  (ws + OFF_IE);
  float* vbuf    = (float*)(ws + OFF_VB);
  float* vnorm   = (float*)(ws + OFF_VN);
  float* cosb    = (float*)(ws + OFF_COS);
  int*   negi    = (int*)  (ws + OFF_NI);
  int*   charsb  = (int*)  (ws + OFF_CH);
  u16*   hsf     = (u16*)  (ws + OFF_HSF);
  u16*   hsb     = (u16*)  (ws + OFF_HSB);
  float* sb      = (float*)(ws + OFF_SB);
  float* echar   = (float*)(ws + OFF_ECH);
  float* part    = (float*)(ws + OFF_PART);
  float* norms2  = (float*)(ws + OFF_NRM);
  u16*   xgf     = (u16*)  (ws + OFF_XGF);
  u16*   xgb     = (u16*)  (ws + OFF_XGB);
  // BN2 stat partials: 16KB at OFF_COS; consumed by k_fcscale (CNN phase)
  // BEFORE k_cos2 overwrites the region with cosb (mining phase) — safe alias.
  float* stp     = (float*)(ws + OFF_COS);

  // ---- prep ----
  k_prep<<<6081, 256, 0, stream>>>(wi_f, wh_f, wi_b, wh_b, a1w, a3w, c2w,
                                   bi_f, bh_f, bi_b, bh_b, a2b, v_emb, pos_v, w2c,
                                   wpf, wpb, a1p, a3p, c2p, bsf, bsb, sb,
                                   vbuf, vnorm, charsb, st, scacc, fcout, norms2, nvocab);

  // ---- CNN ----
  k_stats1<<<512, 256, 0, stream>>>(img, scacc);
  k_fold1<<<1, 64, 0, stream>>>(scacc, c1w, c1b, g1, b1, c1p, st+520, stp);
  k_conv12<<<NIMG, 512, 0, stream>>>(img, c1p, st+520, c2p, c2b, flat2, stp);
  k_fcscale<<<1024, 256, 0, stream>>>(fcw, stp, g2, fcp);
  k_gemm_mfma<<<dim3(32, 4), 512, 0, stream>>>(flat2, nullptr, fcp, nullptr, fcout,
                                               nullptr, nullptr, 2048, 2048, 2);
  k_bn1d_fused<<<128, 256, 0, stream>>>(fcout, g3, b3, imgemb);
  k_xproj<<<dim3(32, 2, 2), 256, 0, stream>>>(imgemb, wpf, wpb, bsf, bsb, xgf, xgb);

  // ---- mining (fp32 exact; R8-proven split kernels, 4096-block grid) ----
  k_cos2<<<dim3(NB, 4), 256, 0, stream>>>(noise, v_emb, vbuf, vnorm, norms2, cosb);
  k_topk<<<NB, 64, 0, stream>>>(cosb, noise, w2c, negi, charsb);

  // ---- BiLSTM: 1408 blocks x 16 rows (R5-proven, frozen) ----
  k_lstm5<<<dim3(1408, 1, 1), 512, 0, stream>>>(charsb, wpf, wpb, xgf, xgb, hsf, hsb);

  // ---- attention ----
  k_gemm_mfma<<<TT*NWRD/64, 512, 0, stream>>>(hsf, hsb, a1p, a1b, nullptr, a2w, sb,
                                              TT*NWRD, 256, 1);
  k_gemm_mfma<<<NWRD/64, 512, 0, stream>>>(hsf, hsb, a3p, a3b, echar, nullptr, sb,
                                           NWRD, 256, 3);

  // ---- loss ----
  k_loss<<<NB, 64, 0, stream>>>(pos_u, u_emb, vbuf, echar, negi, v_emb, part);
  k_final<<<1, 256, 0, stream>>>(part, (float*)d_out);
}

// Round 11
// 207.240 us; speedup vs baseline: 1.0357x; 1.0163x over previous
//
#include <hip/hip_runtime.h>
#include <math.h>

// ---------------- model dims ----------------
#define NIMG   2048
#define EMB    128
#define NB     1024
#define WCTX   6
#define CPW    5
#define NEG    5
#define MNOISE 512
#define NWRD   11264
#define NPOSW  6144
#define TT     5

typedef __bf16 bf16x8 __attribute__((ext_vector_type(8)));
typedef float  f32x4  __attribute__((ext_vector_type(4)));
typedef float  f32x16 __attribute__((ext_vector_type(16)));

__device__ __forceinline__ float sigf(float x){ return __fdividef(1.0f, 1.0f+__expf(-x)); }
__device__ __forceinline__ float ftanh(float x){
  float xc = fminf(15.f, fmaxf(-15.f, x));
  float t = __expf(2.f*xc);
  return __fdividef(t - 1.f, t + 1.f);
}
__device__ __forceinline__ float splus(float z){
  return (z > 0.0f) ? z + log1pf(expf(-z)) : log1pf(expf(z));
}
__device__ __forceinline__ float clip10(float x){ return fminf(10.0f, fmaxf(-10.0f, x)); }
__device__ __forceinline__ float wsum64(float v){
  #pragma unroll
  for (int m = 1; m < 64; m <<= 1) v += __shfl_xor(v, m);
  return v;
}
__device__ __forceinline__ unsigned short f2b(float x){
  union { float f; unsigned u; } v; v.f = x;
  unsigned r = v.u + 0x7fff + ((v.u >> 16) & 1);
  return (unsigned short)(r >> 16);
}
__device__ __forceinline__ float b2f(unsigned short h){
  union { unsigned u; float f; } v; v.u = ((unsigned)h) << 16; return v.f;
}
__device__ __forceinline__ bf16x8 as_bf(uint4 u){
  union { uint4 q; bf16x8 v; } c; c.q = u; return c.v;
}

// ---------------- mega prep ----------------
__global__ void k_prep(
  const float* __restrict__ wi_f, const float* __restrict__ wh_f,
  const float* __restrict__ wi_b, const float* __restrict__ wh_b,
  const float* __restrict__ a1w, const float* __restrict__ a3w,
  const float* __restrict__ c2w,
  const float* __restrict__ bi_f, const float* __restrict__ bh_f,
  const float* __restrict__ bi_b, const float* __restrict__ bh_b,
  const float* __restrict__ a2b, const float* __restrict__ v_emb,
  const int* __restrict__ pos_v, const int* __restrict__ w2c,
  unsigned short* __restrict__ wpf, unsigned short* __restrict__ wpb,
  unsigned short* __restrict__ a1p, unsigned short* __restrict__ a3p,
  unsigned short* __restrict__ c2p,
  float* __restrict__ bsf, float* __restrict__ bsb, float* __restrict__ sbuf,
  float* __restrict__ vbuf, float* __restrict__ vnorm,
  int* __restrict__ chars, float* __restrict__ st, float* __restrict__ scacc,
  float* __restrict__ fcout, float* __restrict__ norms2, int nvocab)
{
  int id = blockIdx.x*256 + threadIdx.x;
  if (id < 262144){
    int dir = id >> 17;
    int lid = id & 131071;
    const float* wi = dir ? wi_b : wi_f;
    const float* wh = dir ? wh_b : wh_f;
    unsigned short* out = dir ? wpb : wpf;
    int j = lid&7, l = (lid>>3)&63, p = (lid>>9)&31, s = lid>>14;
    int wn = p>>3, nf = p&7;
    int gate = nf&3, jb = wn*2 + (nf>>2);
    int n = gate*128 + jb*16 + (l&15);
    int k = s*32 + ((l>>4)<<3) + j;
    float v = (k < 128) ? wi[n*128+k] : wh[n*128 + (k-128)];
    out[lid] = f2b(v);
  } else if (id < 327680){
    int lid = id - 262144;
    int seg = lid >> 15;
    int pid = lid & 32767;
    const float* W = seg ? a3w : a1w;
    unsigned short* out = seg ? a3p : a1p;
    int j = pid&7, l = (pid>>3)&63, rest = pid>>9;
    int p = rest & 7, s = rest >> 3;
    int n = p*16 + (l&15);
    int k = s*32 + ((l>>4)<<3) + j;
    out[pid] = f2b(W[n*256 + k]);
  } else if (id < 336896){
    int pid = id - 327680;
    int j = pid & 7, l = (pid >> 3) & 63, p = (pid >> 9) & 1, t9 = pid >> 10;
    int oc = p*16 + (l & 15), ic = ((l >> 4) << 3) + j;
    c2p[pid] = f2b(c2w[oc*288 + ic*9 + t9]);
  } else if (id < 337408){
    int i = id - 336896;
    bsf[i] = bi_f[i] + bh_f[i];
    bsb[i] = bi_b[i] + bh_b[i];
  } else if (id < 393728){
    int i = id - 337408;
    sbuf[i] = a2b[0];
  } else if (id < 459264){
    int b = (id - 393728) >> 6;
    int l = id & 63;
    float s0 = 0.f, s1 = 0.f;
    for (int w = 0; w < WCTX; w++){
      int vid = pos_v[b*WCTX + w];
      s0 += v_emb[(size_t)vid*128 + l];
      s1 += v_emb[(size_t)vid*128 + 64 + l];
    }
    s0 *= (1.f/6.f); s1 *= (1.f/6.f);
    vbuf[b*128 + l] = s0; vbuf[b*128 + 64 + l] = s1;
    float nn = wsum64(s0*s0 + s1*s1);
    if (l == 0) vnorm[b] = sqrtf(nn);
  } else if (id < 489984){
    int i = id - 459264;
    int wi_ = i / CPW, t = i - wi_*CPW;
    chars[i] = w2c[pos_v[wi_]*CPW + t];
  } else if (id < 491008){
    st[id - 489984] = 0.f;
  } else if (id < 494464){
    scacc[id - 491008] = 0.f;
  } else if (id < 756608){
    fcout[id - 494464] = 0.f;
  } else if (id < 1556608){
    int lid = id - 756608;
    int row = lid >> 4, s = id & 15;
    if (row < nvocab){
      const float4* vp = (const float4*)(v_emb + (size_t)row*128 + s*8);
      float4 x0 = vp[0], x1 = vp[1];
      float q = x0.x*x0.x + x0.y*x0.y + x0.z*x0.z + x0.w*x0.w
              + x1.x*x1.x + x1.y*x1.y + x1.z*x1.z + x1.w*x1.w;
      q += __shfl_xor(q, 1); q += __shfl_xor(q, 2);
      q += __shfl_xor(q, 4); q += __shfl_xor(q, 8);
      if (s == 0) norms2[row] = q;
    }
  }
}

// ---------------- conv1 stats: 4 images per block ----------------
__global__ __launch_bounds__(256) void k_stats1(
    const float* __restrict__ img, float* __restrict__ SC)
{
  __shared__ float im[1444];
  __shared__ float SCw[4][54];
  int tid = threadIdx.x;
  float S[9], C[45];
  #pragma unroll
  for (int a = 0; a < 9; a++) S[a] = 0.f;
  #pragma unroll
  for (int a = 0; a < 45; a++) C[a] = 0.f;
  for (int ii = 0; ii < 4; ii++){
    int n = blockIdx.x*4 + ii;
    const float* ip = img + (size_t)n*1444;
    __syncthreads();
    for (int i = tid; i < 1444; i += 256) im[i] = ip[i];
    __syncthreads();
    for (int p = tid; p < 1296; p += 256){
      int oh = p/36, ow = p - oh*36;
      float P[9];
      #pragma unroll
      for (int i = 0; i < 3; i++)
        #pragma unroll
        for (int j = 0; j < 3; j++)
          P[i*3+j] = im[(oh+i)*38 + ow + j];
      int idx = 0;
      #pragma unroll
      for (int a = 0; a < 9; a++){
        S[a] += P[a];
        #pragma unroll
        for (int b = a; b < 9; b++){ C[idx] += P[a]*P[b]; idx++; }
      }
    }
  }
  #pragma unroll
  for (int a = 0; a < 9; a++) S[a] = wsum64(S[a]);
  #pragma unroll
  for (int a = 0; a < 45; a++) C[a] = wsum64(C[a]);
  if ((tid & 63) == 0){
    int w = tid >> 6;
    #pragma unroll
    for (int a = 0; a < 9; a++) SCw[w][a] = S[a];
    #pragma unroll
    for (int a = 0; a < 45; a++) SCw[w][9+a] = C[a];
  }
  __syncthreads();
  if (tid < 54){
    float v = SCw[0][tid] + SCw[1][tid] + SCw[2][tid] + SCw[3][tid];
    atomicAdd(&SC[tid*64 + (blockIdx.x & 63)], v);
  }
}

// ---------------- BN1 finalize + fold into conv1 weights/bias ----------------
// also zeroes the stp partial buffer for k_conv12 (runs right before it)
__global__ void k_fold1(const float* __restrict__ SC, const float* __restrict__ c1w,
                        const float* __restrict__ c1b, const float* __restrict__ g1,
                        const float* __restrict__ b1,
                        unsigned short* __restrict__ c1p, float* __restrict__ bias1c,
                        float* __restrict__ stp)
{
  __shared__ float S[9], C[45];
  __shared__ float scs[32];
  int tid = threadIdx.x;   // 64
  #pragma unroll
  for (int k = 0; k < 64; k++) stp[k*64 + tid] = 0.f;
  if (tid < 54){
    float acc = 0.f;
    for (int s = 0; s < 64; s++) acc += SC[tid*64 + s];
    if (tid < 9) S[tid] = acc; else C[tid-9] = acc;
  }
  __syncthreads();
  if (tid < 32){
    const float invN = 1.0f/2654208.0f;
    float w[9];
    #pragma unroll
    for (int a = 0; a < 9; a++) w[a] = c1w[tid*9+a];
    float b = c1b[tid];
    float sum = 0.f;
    #pragma unroll
    for (int a = 0; a < 9; a++) sum += w[a]*S[a];
    float sq = 0.f; int idx = 0;
    #pragma unroll
    for (int a = 0; a < 9; a++)
      #pragma unroll
      for (int bb_ = a; bb_ < 9; bb_++){
        float f = (bb_ == a) ? w[a]*w[a] : 2.f*w[a]*w[bb_];
        sq += f*C[idx]; idx++;
      }
    float Epre = sum*invN;
    float var = sq*invN - Epre*Epre;
    float m = Epre + b;
    float sc = g1[tid]*rsqrtf(var + 1e-5f);
    scs[tid] = sc;
    bias1c[tid] = sc*b + (b1[tid] - m*sc);
  }
  __syncthreads();
  {
    int l = tid;
    int ch = l & 31;
    float sc = scs[ch];
    #pragma unroll
    for (int j = 0; j < 8; j++){
      int k = ((l >> 5) << 3) + j;
      int kh = k >> 2, kw = k & 3;
      float v = (kh < 3 && kw < 3) ? c1w[ch*9 + kh*3 + kw]*sc : 0.f;
      c1p[l*8+j] = f2b(v);
    }
  }
}

// ---------------- fused conv1+conv2 ----------------
// R3 structure (512 threads; bfr[9] loaded in one burst after the mid barrier
// — keeps c2pack L2-resident, FETCH ~6MB) + spread BN2-stat atomics (64
// slots, folded by k_fold2). R8-measured best configuration.
__global__ __launch_bounds__(512) void k_conv12(
    const float* __restrict__ img, const unsigned short* __restrict__ c1p,
    const float* __restrict__ bias1c, const unsigned short* __restrict__ c2pack,
    const float* __restrict__ c2b,
    unsigned short* __restrict__ flat2, float* __restrict__ stp)
{
  __shared__ __align__(16) unsigned short Ai[1520];
  __shared__ __align__(16) unsigned short Bi[1520];
  __shared__ __align__(16) unsigned short Pt[324*32];
  __shared__ float lsum[32], lsq[32];
  int n = blockIdx.x, tid = threadIdx.x;
  if (tid < 190){
    int r = tid/5, c = tid - r*5;
    if (c < 2) Ai[r*40 + 38 + c] = 0;
    else       Bi[r*40 + 37 + (c-2)] = 0;
  }
  if (tid >= 192 && tid < 224){ lsum[tid-192] = 0.f; }
  if (tid >= 224 && tid < 256){ lsq[tid-224] = 0.f; }
  const float4* ip4 = (const float4*)(img + (size_t)n*1444);
  for (int i = tid; i < 361; i += 512){
    float4 v = ip4[i];
    int flat = i*4;
    const float* pv = (const float*)&v;
    #pragma unroll
    for (int e = 0; e < 4; e++){
      int f = flat + e;
      int r = f / 38, c = f - r*38;
      unsigned short h = f2b(pv[e]);
      Ai[r*40 + c] = h;
      if (c) Bi[r*40 + c - 1] = h;
    }
  }
  __syncthreads();
  int l = tid & 63, w = tid >> 6;
  {
    int hi = l >> 5;
    int ch = l & 31;
    int r31 = l & 31;
    int member = r31 & 3;
    const unsigned short* P = (member & 1) ? Bi : Ai;
    int rowoff = (member >> 1) * 40;
    bf16x8 bw = as_bf(*(const uint4*)(c1p + (size_t)l*8));
    float bias = bias1c[ch];
    int inoff = (ch & 7)*2;
    int chgrp = ch >> 3;
    #pragma unroll 2
    for (int g = w; g < 41; g += 8){
      int ql = g*8 + (r31 >> 2);
      if (ql > 323) ql = 323;
      int ph = ql/18, pw = ql - ph*18;
      int off = (2*ph)*40 + rowoff + 2*pw;
      uint4 a = (uint4){0u,0u,0u,0u};
      if (hi == 0){
        const unsigned* p0 = (const unsigned*)(P + off);
        const unsigned* p1 = (const unsigned*)(P + off + 40);
        a.x = p0[0]; a.y = p0[1]; a.z = p1[0]; a.w = p1[1];
      } else {
        const unsigned* p2 = (const unsigned*)(P + off + 80);
        a.x = p2[0]; a.y = p2[1];
      }
      f32x16 acc = __builtin_amdgcn_mfma_f32_32x32x16_bf16(
          as_bf(a), bw,
          (f32x16){0.f,0.f,0.f,0.f,0.f,0.f,0.f,0.f,0.f,0.f,0.f,0.f,0.f,0.f,0.f,0.f},
          0, 0, 0);
      #pragma unroll
      for (int rg = 0; rg < 4; rg++){
        int qo = g*8 + rg*2 + hi;
        if (qo < 324){
          float v0 = acc[rg*4+0]+bias, v1 = acc[rg*4+1]+bias;
          float v2 = acc[rg*4+2]+bias, v3 = acc[rg*4+3]+bias;
          float mx = fmaxf(fmaxf(v0,v1), fmaxf(v2,v3));
          *(unsigned short*)((char*)Pt + qo*64 + (((chgrp ^ (qo & 3)) << 4) + inoff)) = f2b(mx);
        }
      }
    }
  }
  __syncthreads();
  int wid = w;
  int wM = wid >> 1, wN = wid & 1;
  bf16x8 bfr[9];
  #pragma unroll
  for (int t9 = 0; t9 < 9; t9++)
    bfr[t9] = as_bf(*(const uint4*)(c2pack + ((size_t)(t9*2 + wN)*64 + l)*8));
  f32x4 acc[4];
  #pragma unroll
  for (int mf = 0; mf < 4; mf++) acc[mf] = (f32x4){0.f,0.f,0.f,0.f};
  #pragma unroll
  for (int t9 = 0; t9 < 9; t9++){
    int kh = t9/3, kw = t9 - (t9/3)*3;
    #pragma unroll
    for (int mf = 0; mf < 4; mf++){
      int pos = wM*64 + mf*16 + (l & 15);
      int oh = pos >> 4, ow = pos & 15;
      int q = (oh + kh)*18 + (ow + kw);
      int slot = ((l >> 4) ^ q) & 3;
      bf16x8 a = as_bf(*(const uint4*)((const char*)Pt + q*64 + slot*16));
      acc[mf] = __builtin_amdgcn_mfma_f32_16x16x32_bf16(a, bfr[t9], acc[mf], 0, 0, 0);
    }
  }
  int oc = wN*16 + (l & 15);
  int qq = l >> 4;
  float bb = c2b[oc];
  float vm[4][4];
  float s = 0.f, sq = 0.f;
  #pragma unroll
  for (int mf = 0; mf < 4; mf++)
    #pragma unroll
    for (int reg = 0; reg < 4; reg++){
      float v = acc[mf][reg] + bb;
      vm[mf][reg] = v;
      s += v; sq += v*v;
    }
  s += __shfl_xor(s,16); sq += __shfl_xor(sq,16);
  s += __shfl_xor(s,32); sq += __shfl_xor(sq,32);
  if (qq == 0){ atomicAdd(&lsum[oc], s); atomicAdd(&lsq[oc], sq); }
  unsigned short* fp = flat2 + (size_t)n*2048 + oc*64;
  #pragma unroll
  for (int mp = 0; mp < 2; mp++){
    int ph = wM*2 + mp;
    float p0 = fmaxf(fmaxf(vm[2*mp][0], vm[2*mp][1]), fmaxf(vm[2*mp+1][0], vm[2*mp+1][1]));
    float p1 = fmaxf(fmaxf(vm[2*mp][2], vm[2*mp][3]), fmaxf(vm[2*mp+1][2], vm[2*mp+1][3]));
    unsigned pk = ((unsigned)f2b(p1) << 16) | (unsigned)f2b(p0);
    *(unsigned*)(fp + ph*8 + qq*2) = pk;
  }
  __syncthreads();
  if (tid < 32){
    int slot = (blockIdx.x & 63)*64;
    atomicAdd(&stp[slot + tid], lsum[tid]);
    atomicAdd(&stp[slot + 32 + tid], lsq[tid]);
  }
}

// ---------------- fold 64-slot BN2 partials into st[128..191] ----------------
__global__ void k_fold2(const float* __restrict__ stp, float* __restrict__ st)
{
  int v = threadIdx.x;   // 64
  float acc = 0.f;
  #pragma unroll 8
  for (int s = 0; s < 64; s++) acc += stp[s*64 + v];
  st[128 + v] = acc;
}

// ---------------- fc pack with BN2 scale folded ----------------
__global__ void k_fcscale(const float* __restrict__ fcw, const float* __restrict__ st,
                          const float* __restrict__ g2, unsigned short* __restrict__ fcp)
{
  int id = blockIdx.x*256 + threadIdx.x;
  if (id >= 262144) return;
  int j = id&7, l = (id>>3)&63, rest = id>>9;
  int p = rest & 7, s = rest >> 3;
  int n = p*16 + (l&15);
  int k = s*32 + ((l>>4)<<3) + j;
  int c = k >> 6;
  float m = st[128+c]*(1.f/524288.f);
  float var = st[160+c]*(1.f/524288.f) - m*m;
  float sc = g2[c]*rsqrtf(var + 1e-5f);
  fcp[id] = f2b(fcw[(size_t)n*2048 + k] * sc);
}

// ---------------- generic MFMA GEMM, N=128 ----------------
__global__ __launch_bounds__(512) void k_gemm_mfma(
    const unsigned short* __restrict__ A0, const unsigned short* __restrict__ A1,
    const unsigned short* __restrict__ wpack, const float* __restrict__ bias,
    float* __restrict__ out, const float* __restrict__ a2w, float* __restrict__ sbuf,
    int M, int K, int fuse)
{
  __shared__ unsigned short At[64*256];
  __shared__ float wt[64][5];
  int tid = threadIdx.x;
  int l = tid & 63, wid = tid >> 6;
  int row0 = blockIdx.x * 64;
  int wm = wid >> 2, wn = wid & 3;
  int kspan = K / gridDim.y;
  int kbeg = blockIdx.y * kspan;
  f32x4 acc[2][2];
  #pragma unroll
  for (int a = 0; a < 2; a++)
    #pragma unroll
    for (int b = 0; b < 2; b++) acc[a][b] = (f32x4){0.f,0.f,0.f,0.f};

  if (fuse == 3){
    if (tid < 64){
      int gr = row0 + tid;
      float sv[TT];
      float mx = -1e30f;
      #pragma unroll
      for (int t = 0; t < TT; t++){ sv[t] = sbuf[t*NWRD + gr]; mx = fmaxf(mx, sv[t]); }
      float sum = 0.f;
      #pragma unroll
      for (int t = 0; t < TT; t++){ sv[t] = __expf(sv[t] - mx); sum += sv[t]; }
      float inv = __fdividef(1.f, sum);
      #pragma unroll
      for (int t = 0; t < TT; t++) wt[tid][t] = sv[t]*inv;
    }
    __syncthreads();
  }

  for (int kc = kbeg; kc < kbeg + kspan; kc += 256){
    #pragma unroll
    for (int it = 0; it < 4; it++){
      int ci = tid + 512*it;
      int r = ci >> 5, c = ci & 31;
      int gr = row0 + r; int k = kc + c*8;
      uint4 v;
      if (fuse == 3){
        int col = (k < 128) ? k : (k - 128);
        const unsigned short* sp = (k < 128) ? A0 : A1;
        float a8[8];
        #pragma unroll
        for (int e = 0; e < 8; e++) a8[e] = 0.f;
        #pragma unroll
        for (int t = 0; t < TT; t++){
          uint4 hv = *(const uint4*)(sp + ((size_t)t*NWRD + gr)*128 + col);
          const unsigned short* ph = (const unsigned short*)&hv;
          float wgt = wt[r][t];
          #pragma unroll
          for (int e = 0; e < 8; e++) a8[e] += wgt * b2f(ph[e]);
        }
        unsigned short o[8];
        #pragma unroll
        for (int e = 0; e < 8; e++) o[e] = f2b(a8[e]);
        v = *(uint4*)o;
      } else {
        const unsigned short* src;
        if (A1) src = (k < 128) ? (A0 + (size_t)gr*128 + k) : (A1 + (size_t)gr*128 + (k-128));
        else    src = A0 + (size_t)gr*K + k;
        v = *(const uint4*)src;
      }
      *(uint4*)((char*)At + r*512 + ((c*16) ^ ((r & 7) << 4))) = v;
    }
    __syncthreads();
    #pragma unroll
    for (int s8 = 0; s8 < 8; s8++){
      int s = (kc >> 5) + s8;
      bf16x8 af[2];
      #pragma unroll
      for (int mf = 0; mf < 2; mf++){
        int r = wm*32 + mf*16 + (l & 15);
        int cb = (s8*4 + (l >> 4)) ^ (r & 7);
        af[mf] = as_bf(*(const uint4*)((const char*)At + r*512 + cb*16));
      }
      #pragma unroll
      for (int nf = 0; nf < 2; nf++){
        bf16x8 bf_ = as_bf(*(const uint4*)(wpack + ((size_t)(s*8 + wn*2 + nf)*64 + l)*8));
        acc[0][nf] = __builtin_amdgcn_mfma_f32_16x16x32_bf16(af[0], bf_, acc[0][nf], 0,0,0);
        acc[1][nf] = __builtin_amdgcn_mfma_f32_16x16x32_bf16(af[1], bf_, acc[1][nf], 0,0,0);
      }
    }
    __syncthreads();
  }
  if (fuse == 0 || fuse == 3){
    #pragma unroll
    for (int mf = 0; mf < 2; mf++)
      #pragma unroll
      for (int nf = 0; nf < 2; nf++)
        #pragma unroll
        for (int reg = 0; reg < 4; reg++){
          int row = row0 + wm*32 + mf*16 + ((l >> 4) << 2) + reg;
          int col = wn*32 + nf*16 + (l & 15);
          out[(size_t)row*128 + col] = acc[mf][nf][reg] + bias[col];
        }
  } else if (fuse == 2){
    #pragma unroll
    for (int mf = 0; mf < 2; mf++)
      #pragma unroll
      for (int nf = 0; nf < 2; nf++)
        #pragma unroll
        for (int reg = 0; reg < 4; reg++){
          int row = row0 + wm*32 + mf*16 + ((l >> 4) << 2) + reg;
          int col = wn*32 + nf*16 + (l & 15);
          atomicAdd(&out[(size_t)row*128 + col], acc[mf][nf][reg]);
        }
  } else {
    float part[2][4];
    #pragma unroll
    for (int mf = 0; mf < 2; mf++)
      #pragma unroll
      for (int reg = 0; reg < 4; reg++){
        float p = 0.f;
        #pragma unroll
        for (int nf = 0; nf < 2; nf++){
          int col = wn*32 + nf*16 + (l & 15);
          p += ftanh(acc[mf][nf][reg] + bias[col]) * a2w[col];
        }
        part[mf][reg] = p;
      }
    #pragma unroll
    for (int msk = 1; msk < 16; msk <<= 1)
      #pragma unroll
      for (int mf = 0; mf < 2; mf++)
        #pragma unroll
        for (int reg = 0; reg < 4; reg++)
          part[mf][reg] += __shfl_xor(part[mf][reg], msk);
    if ((l & 15) == 0){
      #pragma unroll
      for (int mf = 0; mf < 2; mf++)
        #pragma unroll
        for (int reg = 0; reg < 4; reg++)
          atomicAdd(&sbuf[row0 + wm*32 + mf*16 + ((l >> 4) << 2) + reg], part[mf][reg]);
    }
  }
}

// ---------------- BN1d fused ----------------
__global__ __launch_bounds__(256) void k_bn1d_fused(const float* __restrict__ fc,
    const float* __restrict__ g3, const float* __restrict__ b3,
    unsigned short* __restrict__ img_emb)
{
  int j = blockIdx.x, tid = threadIdx.x;
  float vr[8];
  float s = 0.f, q = 0.f;
  #pragma unroll
  for (int u = 0; u < 8; u++){
    float v = fc[(u*256 + tid)*128 + j];
    vr[u] = v; s += v; q += v*v;
  }
  s = wsum64(s); q = wsum64(q);
  __shared__ float rs[4], rq[4];
  if ((tid & 63) == 0){ rs[tid>>6] = s; rq[tid>>6] = q; }
  __syncthreads();
  float S = rs[0]+rs[1]+rs[2]+rs[3];
  float Q = rq[0]+rq[1]+rq[2]+rq[3];
  float m = S*(1.f/2048.f);
  float var = Q*(1.f/2048.f) - m*m;
  float sc = g3[j]*rsqrtf(var + 1e-5f);
  float sh = b3[j] - m*sc;
  #pragma unroll
  for (int u = 0; u < 8; u++)
    img_emb[(u*256 + tid)*128 + j] = f2b(fmaxf(0.f, vr[u]*sc + sh));
}

// ---------------- LSTM x-projection -> bf16 packed gates ----------------
__global__ __launch_bounds__(256) void k_xproj(
    const unsigned short* __restrict__ xemb,
    const unsigned short* __restrict__ wpf, const unsigned short* __restrict__ wpb,
    const float* __restrict__ bsf, const float* __restrict__ bsb,
    unsigned short* __restrict__ xgf, unsigned short* __restrict__ xgb)
{
  __shared__ unsigned short At[64*128];
  int dir = blockIdx.z;
  const unsigned short* wpack = dir ? wpb : wpf;
  const float* bsum = dir ? bsb : bsf;
  unsigned short* xg = dir ? xgb : xgf;
  int tid = threadIdx.x;
  int l = tid & 63, wid = tid >> 6;
  int row0 = blockIdx.x * 64;
  int wm = wid >> 1;
  int wn = blockIdx.y*2 + (wid & 1);
  #pragma unroll
  for (int it = 0; it < 4; it++){
    int ci = tid + 256*it;
    int r = ci >> 4, c = ci & 15;
    uint4 v = *(const uint4*)(xemb + (size_t)(row0 + r)*128 + c*8);
    *(uint4*)((char*)At + r*256 + ((c*16) ^ ((r & 7) << 4))) = v;
  }
  __syncthreads();
  f32x4 acc[2][8];
  #pragma unroll
  for (int a = 0; a < 2; a++)
    #pragma unroll
    for (int b = 0; b < 8; b++) acc[a][b] = (f32x4){0.f,0.f,0.f,0.f};
  #pragma unroll
  for (int s4 = 0; s4 < 4; s4++){
    bf16x8 af[2];
    #pragma unroll
    for (int mf = 0; mf < 2; mf++){
      int r = wm*32 + mf*16 + (l & 15);
      int cb = (s4*4 + (l >> 4)) ^ (r & 7);
      af[mf] = as_bf(*(const uint4*)((const char*)At + r*256 + cb*16));
    }
    #pragma unroll
    for (int nf = 0; nf < 8; nf++){
      bf16x8 bf_ = as_bf(*(const uint4*)(wpack + ((size_t)(s4*32 + wn*8 + nf)*64 + l)*8));
      acc[0][nf] = __builtin_amdgcn_mfma_f32_16x16x32_bf16(af[0], bf_, acc[0][nf], 0,0,0);
      acc[1][nf] = __builtin_amdgcn_mfma_f32_16x16x32_bf16(af[1], bf_, acc[1][nf], 0,0,0);
    }
  }
  #pragma unroll
  for (int mf = 0; mf < 2; mf++)
    #pragma unroll
    for (int reg = 0; reg < 4; reg++){
      int gr = row0 + wm*32 + mf*16 + ((l >> 4) << 2) + reg;
      unsigned short* xrow = xg + (size_t)gr*512;
      #pragma unroll
      for (int js = 0; js < 2; js++){
        int jl = wn*32 + js*16 + (l & 15);
        unsigned short o[4];
        o[0] = f2b(acc[mf][js*4+0][reg] + bsum[jl]);
        o[1] = f2b(acc[mf][js*4+1][reg] + bsum[128+jl]);
        o[2] = f2b(acc[mf][js*4+2][reg] + bsum[256+jl]);
        o[3] = f2b(acc[mf][js*4+3][reg] + bsum[384+jl]);
        *(uint2*)(xrow + jl*4) = *(uint2*)o;
      }
    }
}

// ---------------- fused 5-step dual-direction LSTM ----------------
// R5-proven version (46.6us), FROZEN: 1408 blocks x one 16-row tile; hh
// weights register-resident (16 frags = 64 VGPR, 8 waves/SIMD); post-barrier
// prefetch of next-step xv gathers; nontemporal hs flush; med3 clamps.
// R6/R7: widening per-block work loses (VGPR >64 halves waves/SIMD).
__global__ __launch_bounds__(512, 4) void k_lstm5(
    const int* __restrict__ chars,
    const unsigned short* __restrict__ wpf, const unsigned short* __restrict__ wpb,
    const unsigned short* __restrict__ xgf, const unsigned short* __restrict__ xgb,
    unsigned short* __restrict__ hsf, unsigned short* __restrict__ hsb)
{
  __shared__ __align__(16) unsigned short At[2][2048];   // 2 x 4KB swizzled h tiles
  __shared__ int cid_s[80];                               // 16 rows x 5 steps
  int b = blockIdx.x;
  int br = b & 7;
  int dir = br >> 2;
  int rblk = (b >> 3)*4 + (br & 3);        // 0..703 per dir
  const unsigned short* wpack = dir ? wpb : wpf;
  const unsigned short* xg = dir ? xgb : xgf;
  unsigned short* hs = dir ? hsb : hsf;
  int tid = threadIdx.x;
  int l = tid & 63, c = tid >> 6;          // c = 16-col h-slice 0..7
  int jl = c*16 + (l & 15);                // global h column
  int row0 = rblk * 16;

  if (tid < 80) cid_s[tid] = chars[row0*CPW + tid];

  bf16x8 wreg[4][4];
  #pragma unroll
  for (int s4 = 0; s4 < 4; s4++)
    #pragma unroll
    for (int g = 0; g < 4; g++)
      wreg[s4][g] = as_bf(*(const uint4*)(wpack + ((size_t)((s4+4)*32 + c*4 + g)*64 + l)*8));

  int frow = tid >> 5, fq = tid & 31;
  int fof = (((fq >> 1) ^ (frow & 7)) << 4) | ((fq & 1) << 3);

  __syncthreads();                          // cid_s ready

  int rbase = (l >> 4) << 2;
  int t0 = dir ? (TT-1) : 0;
  uint2 xv[4], xvn[4];
  #pragma unroll
  for (int reg = 0; reg < 4; reg++)
    xv[reg] = *(const uint2*)(xg + (size_t)cid_s[(rbase+reg)*CPW + t0]*512 + jl*4);

  float creg[4];
  #pragma unroll
  for (int reg = 0; reg < 4; reg++) creg[reg] = 0.f;
  int tprev = t0;

  #pragma unroll
  for (int tF = 0; tF < TT; tF++){
    int t = dir ? (TT-1-tF) : tF;
    f32x4 acc[4];
    if (tF > 0){
      __syncthreads();
      const unsigned short* buf = At[(tF-1) & 1];
      uint2 hv = *(const uint2*)((const char*)buf + tid*8);
      {
        union { uint2 v; unsigned long long q; } cv; cv.v = hv;
        __builtin_nontemporal_store(cv.q,
          (unsigned long long*)((char*)(hs + (size_t)tprev*NWRD*128 + (size_t)(row0 + frow)*128) + fof));
      }
      if (tF + 1 < TT){
        int tn = dir ? (TT-2-tF) : (tF+1);
        #pragma unroll
        for (int reg = 0; reg < 4; reg++)
          xvn[reg] = *(const uint2*)(xg + (size_t)cid_s[(rbase+reg)*CPW + tn]*512 + jl*4);
      }
      #pragma unroll
      for (int g = 0; g < 4; g++) acc[g] = (f32x4){0.f,0.f,0.f,0.f};
      #pragma unroll
      for (int s4 = 0; s4 < 4; s4++){
        int r = l & 15;
        int cb = (s4*4 + (l >> 4)) ^ (r & 7);
        bf16x8 af = as_bf(*(const uint4*)((const char*)buf + r*256 + cb*16));
        #pragma unroll
        for (int g = 0; g < 4; g++)
          acc[g] = __builtin_amdgcn_mfma_f32_16x16x32_bf16(af, wreg[s4][g], acc[g], 0,0,0);
      }
    } else {
      int tn = dir ? (TT-2) : 1;
      #pragma unroll
      for (int reg = 0; reg < 4; reg++)
        xvn[reg] = *(const uint2*)(xg + (size_t)cid_s[(rbase+reg)*CPW + tn]*512 + jl*4);
      #pragma unroll
      for (int g = 0; g < 4; g++) acc[g] = (f32x4){0.f,0.f,0.f,0.f};
    }
    unsigned short* wb = At[tF & 1];
    #pragma unroll
    for (int reg = 0; reg < 4; reg++){
      int rloc = ((l >> 4) << 2) + reg;
      const unsigned short* xs = (const unsigned short*)&xv[reg];
      float ig = acc[0][reg] + b2f(xs[0]);
      float fg = acc[1][reg] + b2f(xs[1]);
      float gg = acc[2][reg] + b2f(xs[2]);
      float og = acc[3][reg] + b2f(xs[3]);
      float co = creg[reg];
      float ei = __expf(-__builtin_amdgcn_fmed3f(ig, -30.f, 30.f));
      float eg = __expf(2.f*__builtin_amdgcn_fmed3f(gg, -15.f, 15.f));
      float sf = __fdividef(1.f, 1.f + __expf(-__builtin_amdgcn_fmed3f(fg, -30.f, 30.f)));
      float itg = __fdividef(eg - 1.f, (1.f + ei)*(eg + 1.f));
      float cn = sf*co + itg;
      float eo = __expf(-__builtin_amdgcn_fmed3f(og, -30.f, 30.f));
      float ec = __expf(2.f*__builtin_amdgcn_fmed3f(cn, -15.f, 15.f));
      float h  = __fdividef(ec - 1.f, (1.f + eo)*(ec + 1.f));
      creg[reg] = cn;
      int byteoff = rloc*256 + ((((jl >> 3) << 4) ^ ((rloc & 7) << 4)) + (jl & 7)*2);
      *(unsigned short*)((char*)wb + byteoff) = f2b(h);
    }
    tprev = t;
    #pragma unroll
    for (int reg = 0; reg < 4; reg++) xv[reg] = xvn[reg];
  }
  __syncthreads();
  const unsigned short* buf = At[(TT-1) & 1];
  uint2 hv = *(const uint2*)((const char*)buf + tid*8);
  {
    union { uint2 v; unsigned long long q; } cv; cv.v = hv;
    __builtin_nontemporal_store(cv.q,
      (unsigned long long*)((char*)(hs + (size_t)tprev*NWRD*128 + (size_t)(row0 + frow)*128) + fof));
  }
}

// ---------------- cosine sims (grid.y = 4) ----------------
__global__ __launch_bounds__(256) void k_cos2(const int* __restrict__ noise,
    const float* __restrict__ v_emb, const float* __restrict__ vbuf,
    const float* __restrict__ vnorm, const float* __restrict__ norms2,
    float* __restrict__ cosb)
{
  int b = blockIdx.x;
  int tid = threadIdx.x;
  int s = tid & 15;
  int rsub = (tid >> 4) & 3;
  int wid = tid >> 6;
  const float4* ep = (const float4*)(vbuf + b*128 + s*8);
  float4 e0 = ep[0], e1 = ep[1];
  float nb = vnorm[b];
  int mbase = blockIdx.y*128 + wid*4 + rsub;
  #pragma unroll 4
  for (int iter = 0; iter < 8; iter++){
    int m = mbase + iter*16;
    int id = noise[b*MNOISE + m];
    const float4* vp = (const float4*)(v_emb + (size_t)id*128 + s*8);
    float4 x0 = vp[0], x1 = vp[1];
    float d = e0.x*x0.x + e0.y*x0.y + e0.z*x0.z + e0.w*x0.w
            + e1.x*x1.x + e1.y*x1.y + e1.z*x1.z + e1.w*x1.w;
    d += __shfl_xor(d, 1); d += __shfl_xor(d, 2);
    d += __shfl_xor(d, 4); d += __shfl_xor(d, 8);
    if (s == 0){
      float q = norms2[id];
      cosb[b*MNOISE + m] = d / fmaxf(nb*sqrtf(q), 1e-8f);
    }
  }
}

// ---------------- top-5 + negative char gather ----------------
__global__ __launch_bounds__(64) void k_topk(const float* __restrict__ cosb,
    const int* __restrict__ noise, const int* __restrict__ w2c,
    int* __restrict__ neg_ids, int* __restrict__ chars)
{
  __shared__ int nid_s[NEG];
  int b = blockIdx.x, l = threadIdx.x;
  float v[8];
  int base = b*MNOISE;
  #pragma unroll
  for (int q = 0; q < 8; q++) v[q] = cosb[base + l + 64*q];
  for (int r = 0; r < NEG; r++){
    float bv = -1e30f; int bidx = 1<<30;
    #pragma unroll
    for (int q = 0; q < 8; q++){
      int idx = l + 64*q;
      if (v[q] > bv || (v[q] == bv && idx < bidx)){ bv = v[q]; bidx = idx; }
    }
    #pragma unroll
    for (int m = 1; m < 64; m <<= 1){
      float ov = __shfl_xor(bv, m);
      int   oi = __shfl_xor(bidx, m);
      if (ov > bv || (ov == bv && oi < bidx)){ bv = ov; bidx = oi; }
    }
    if (l == 0){
      int nid = noise[base + bidx];
      neg_ids[b*NEG + r] = nid;
      nid_s[r] = nid;
    }
    int qsel = bidx >> 6;
    #pragma unroll
    for (int q = 0; q < 8; q++)
      if (q == qsel && (bidx & 63) == l) v[q] = -1e30f;
  }
  __syncthreads();
  if (l < NEG*CPW){
    int k = l / CPW, t = l - k*CPW;
    chars[(NPOSW + b*NEG + k)*CPW + t] = w2c[nid_s[k]*CPW + t];
  }
}

// ---------------- loss ----------------
__global__ __launch_bounds__(64) void k_loss(const int* __restrict__ pos_u,
    const float* __restrict__ u_emb, const float* __restrict__ vbuf,
    const float* __restrict__ echar, const int* __restrict__ neg_ids,
    const float* __restrict__ v_emb, float* __restrict__ part)
{
  int b = blockIdx.x, l = threadIdx.x;
  int pu = pos_u[b];
  float eu0 = u_emb[pu*128 + l], eu1 = u_emb[pu*128 + 64 + l];
  float c0 = 0.f, c1 = 0.f;
  for (int w = 0; w < WCTX; w++){
    int r = b*WCTX + w;
    c0 += echar[r*128 + l]; c1 += echar[r*128 + 64 + l];
  }
  c0 *= (1.f/6.f); c1 *= (1.f/6.f);
  float d1 = wsum64(eu0*c0 + eu1*c1);
  float d2 = wsum64(eu0*vbuf[b*128 + l] + eu1*vbuf[b*128 + 64 + l]);
  float tot = splus(-clip10(d1)) + splus(-clip10(d2));
  for (int k = 0; k < NEG; k++){
    int r = NPOSW + b*NEG + k;
    float dc = wsum64(eu0*echar[r*128 + l] + eu1*echar[r*128 + 64 + l]);
    int nid = neg_ids[b*NEG + k];
    float dn = wsum64(eu0*v_emb[nid*128 + l] + eu1*v_emb[nid*128 + 64 + l]);
    tot += splus(clip10(dc)) + splus(clip10(dn));
  }
  if (l == 0) part[b] = tot;
}

__global__ __launch_bounds__(256) void k_final(const float* __restrict__ part, float* __restrict__ out)
{
  int tid = threadIdx.x;
  float s = part[tid] + part[tid+256] + part[tid+512] + part[tid+768];
  s = wsum64(s);
  __shared__ float r[4];
  if ((tid & 63) == 0) r[tid>>6] = s;
  __syncthreads();
  if (tid == 0) out[0] = (r[0]+r[1]+r[2]+r[3]) * (1.0f/1024.0f);
}

// ---------------- launch ----------------
extern "C" void kernel_launch(void* const* d_in, const int* in_sizes, int n_in,
                              void* d_out, int out_size, void* d_ws, size_t ws_size,
                              hipStream_t stream)
{
  (void)n_in; (void)out_size; (void)ws_size;
  const int*   pos_u  = (const int*)  d_in[0];
  const int*   pos_v  = (const int*)  d_in[1];
  const int*   noise  = (const int*)  d_in[2];
  const int*   w2c    = (const int*)  d_in[3];
  const float* img    = (const float*)d_in[4];
  const float* u_emb  = (const float*)d_in[5];
  const float* v_emb  = (const float*)d_in[6];
  const float* c1w    = (const float*)d_in[7];
  const float* c1b    = (const float*)d_in[8];
  const float* g1     = (const float*)d_in[9];
  const float* b1     = (const float*)d_in[10];
  const float* c2w    = (const float*)d_in[11];
  const float* c2b    = (const float*)d_in[12];
  const float* g2     = (const float*)d_in[13];
  const float* b2     = (const float*)d_in[14];
  const float* fcw    = (const float*)d_in[15];
  const float* fcb    = (const float*)d_in[16];
  const float* g3     = (const float*)d_in[17];
  const float* b3     = (const float*)d_in[18];
  const float* wi_f   = (const float*)d_in[19];
  const float* wh_f   = (const float*)d_in[20];
  const float* bi_f   = (const float*)d_in[21];
  const float* bh_f   = (const float*)d_in[22];
  const float* wi_b   = (const float*)d_in[23];
  const float* wh_b   = (const float*)d_in[24];
  const float* bi_b   = (const float*)d_in[25];
  const float* bh_b   = (const float*)d_in[26];
  const float* a1w    = (const float*)d_in[27];
  const float* a1b    = (const float*)d_in[28];
  const float* a2w    = (const float*)d_in[29];
  const float* a2b    = (const float*)d_in[30];
  const float* a3w    = (const float*)d_in[31];
  const float* a3b    = (const float*)d_in[32];
  (void)fcb; (void)b2;
  int nvocab = in_sizes[6] / 128;

  char* ws = (char*)d_ws;
  typedef unsigned short u16;
  constexpr size_t OFF_ST   = 0;
  constexpr size_t OFF_WPF  = 4096;
  constexpr size_t OFF_WPB  = OFF_WPF + 262144;
  constexpr size_t OFF_A1P  = OFF_WPB + 262144;
  constexpr size_t OFF_A3P  = OFF_A1P + 65536;
  constexpr size_t OFF_FCP  = OFF_A3P + 65536;
  constexpr size_t OFF_C2P  = OFF_FCP + 524288;
  constexpr size_t OFF_C1P  = OFF_C2P + 18432;
  constexpr size_t OFF_BSF  = OFF_C1P + 2048;
  constexpr size_t OFF_BSB  = OFF_BSF + 2048;
  constexpr size_t OFF_SC   = OFF_BSB + 2048;
  constexpr size_t OFF_HSF  = OFF_SC + 14336;
  constexpr size_t OFF_HSB  = OFF_HSF + 14417920;
  constexpr size_t OFF_FL2  = OFF_HSB + 14417920;
  constexpr size_t OFF_ECH  = OFF_FL2 + 5767168;
  constexpr size_t OFF_FC   = OFF_ECH + 5767168;
  constexpr size_t OFF_IE   = OFF_FC  + 1048576;
  constexpr size_t OFF_VB   = OFF_IE  + 524288;
  constexpr size_t OFF_VN   = OFF_VB  + 524288;
  constexpr size_t OFF_COS  = OFF_VN  + 4096;
  constexpr size_t OFF_NI   = OFF_COS + 2097152;
  constexpr size_t OFF_CH   = OFF_NI  + 20480;
  constexpr size_t OFF_SB   = OFF_CH  + 225280;
  constexpr size_t OFF_PART = OFF_SB  + 225280;
  constexpr size_t OFF_NRM  = OFF_PART + 4096;
  constexpr size_t OFF_XGF  = OFF_NRM + 204800;
  constexpr size_t OFF_XGB  = OFF_XGF + 2097152;

  float* st      = (float*)(ws + OFF_ST);
  u16*   wpf     = (u16*)  (ws + OFF_WPF);
  u16*   wpb     = (u16*)  (ws + OFF_WPB);
  u16*   a1p     = (u16*)  (ws + OFF_A1P);
  u16*   a3p     = (u16*)  (ws + OFF_A3P);
  u16*   fcp     = (u16*)  (ws + OFF_FCP);
  u16*   c2p     = (u16*)  (ws + OFF_C2P);
  u16*   c1p     = (u16*)  (ws + OFF_C1P);
  float* bsf     = (float*)(ws + OFF_BSF);
  float* bsb     = (float*)(ws + OFF_BSB);
  float* scacc   = (float*)(ws + OFF_SC);
  u16*   flat2   = (u16*)  (ws + OFF_FL2);
  float* fcout   = (float*)(ws + OFF_FC);
  u16*   imgemb  = (u16*)  (ws + OFF_IE);
  float* vbuf    = (float*)(ws + OFF_VB);
  float* vnorm   = (float*)(ws + OFF_VN);
  float* cosb    = (float*)(ws + OFF_COS);
  int*   negi    = (int*)  (ws + OFF_NI);
  int*   charsb  = (int*)  (ws + OFF_CH);
  u16*   hsf     = (u16*)  (ws + OFF_HSF);
  u16*   hsb     = (u16*)  (ws + OFF_HSB);
  float* sb      = (float*)(ws + OFF_SB);
  float* echar   = (float*)(ws + OFF_ECH);
  float* part    = (float*)(ws + OFF_PART);
  float* norms2  = (float*)(ws + OFF_NRM);
  u16*   xgf     = (u16*)  (ws + OFF_XGF);
  u16*   xgb     = (u16*)  (ws + OFF_XGB);
  // BN2 stat partials: 16KB at OFF_COS; consumed by k_fold2 (CNN phase)
  // BEFORE k_cos2 overwrites the region with cosb (mining phase) — safe alias.
  float* stp     = (float*)(ws + OFF_COS);

  // ---- prep ----
  k_prep<<<6081, 256, 0, stream>>>(wi_f, wh_f, wi_b, wh_b, a1w, a3w, c2w,
                                   bi_f, bh_f, bi_b, bh_b, a2b, v_emb, pos_v, w2c,
                                   wpf, wpb, a1p, a3p, c2p, bsf, bsb, sb,
                                   vbuf, vnorm, charsb, st, scacc, fcout, norms2, nvocab);

  // ---- CNN ----
  k_stats1<<<512, 256, 0, stream>>>(img, scacc);
  k_fold1<<<1, 64, 0, stream>>>(scacc, c1w, c1b, g1, b1, c1p, st+520, stp);
  k_conv12<<<NIMG, 512, 0, stream>>>(img, c1p, st+520, c2p, c2b, flat2, stp);
  k_fold2<<<1, 64, 0, stream>>>(stp, st);
  k_fcscale<<<1024, 256, 0, stream>>>(fcw, st, g2, fcp);
  k_gemm_mfma<<<dim3(32, 4), 512, 0, stream>>>(flat2, nullptr, fcp, nullptr, fcout,
                                               nullptr, nullptr, 2048, 2048, 2);
  k_bn1d_fused<<<128, 256, 0, stream>>>(fcout, g3, b3, imgemb);
  k_xproj<<<dim3(32, 2, 2), 256, 0, stream>>>(imgemb, wpf, wpb, bsf, bsb, xgf, xgb);

  // ---- mining (fp32 exact) ----
  k_cos2<<<dim3(NB, 4), 256, 0, stream>>>(noise, v_emb, vbuf, vnorm, norms2, cosb);
  k_topk<<<NB, 64, 0, stream>>>(cosb, noise, w2c, negi, charsb);

  // ---- BiLSTM: 1408 blocks x 16 rows (R5-proven, frozen) ----
  k_lstm5<<<dim3(1408, 1, 1), 512, 0, stream>>>(charsb, wpf, wpb, xgf, xgb, hsf, hsb);

  // ---- attention ----
  k_gemm_mfma<<<TT*NWRD/64, 512, 0, stream>>>(hsf, hsb, a1p, a1b, nullptr, a2w, sb,
                                              TT*NWRD, 256, 1);
  k_gemm_mfma<<<NWRD/64, 512, 0, stream>>>(hsf, hsb, a3p, a3b, echar, nullptr, sb,
                                           NWRD, 256, 3);

  // ---- loss ----
  k_loss<<<NB, 64, 0, stream>>>(pos_u, u_emb, vbuf, echar, negi, v_emb, part);
  k_final<<<1, 256, 0, stream>>>(part, (float*)d_out);
}